// Round 5
// baseline (203.008 us; speedup 1.0000x reference)
//
#include <hip/hip_runtime.h>
#include <cmath>

// ---------------------------------------------------------------------------
// 2-layer GAT, N=10000, E=160000(+self loops in CSR), F_IN=256 ->
// [8x128 concat]=1024 -> ELU -> [1x64]. Split-bf16 MFMA GEMMs (3-term),
// tile-linear packed operands, split-K GEMM2. Aggregation: edge-parallel
// e-precompute + barrier-free one-wave-per-node gather, deferred normalize.
// ---------------------------------------------------------------------------

typedef short bf16x8 __attribute__((ext_vector_type(8)));
typedef float f32x4 __attribute__((ext_vector_type(4)));
typedef unsigned short u16x8 __attribute__((ext_vector_type(8)));

__device__ __forceinline__ float lrelu(float x) { return x > 0.f ? x : 0.2f * x; }
__device__ __forceinline__ float b2f(unsigned short h) {
  return __uint_as_float(((unsigned)h) << 16);
}
__device__ __forceinline__ unsigned short f2bf(float f) {
  unsigned u = __float_as_uint(f);
  u += 0x7FFFu + ((u >> 16) & 1u);
  return (unsigned short)(u >> 16);
}

#define GLOAD_LDS16(gsrc, ldst)                                              \
  __builtin_amdgcn_global_load_lds(                                          \
      (const __attribute__((address_space(1))) unsigned int*)(gsrc),         \
      (__attribute__((address_space(3))) unsigned int*)(ldst), 16, 0, 0)

// ---- CSR build (self-loops included: tot[i] = edge_deg[i] + 1) ------------

__global__ __launch_bounds__(256) void count_kernel(const int* __restrict__ ei,
                                                    int* __restrict__ counts, int E) {
  int e = blockIdx.x * 256 + threadIdx.x;
  if (e < E) atomicAdd(&counts[ei[E + e]], 1);
}

// two-level scan over v[i] = counts[i] + 1
__global__ __launch_bounds__(256) void scan_blk(const int* __restrict__ counts,
                                                int* __restrict__ offsets,
                                                int* __restrict__ bsum, int n) {
  __shared__ int lds[256];
  int b = blockIdx.x, t = threadIdx.x, i = b * 256 + t;
  int v = (i < n) ? counts[i] + 1 : 0;
  lds[t] = v;
  __syncthreads();
  for (int off = 1; off < 256; off <<= 1) {
    int tv = (t >= off) ? lds[t - off] : 0;
    __syncthreads();
    lds[t] += tv;
    __syncthreads();
  }
  if (i < n) offsets[i] = lds[t] - v;
  if (t == 255) bsum[b] = lds[255];
}

__global__ __launch_bounds__(256) void scan_top(const int* __restrict__ bsum,
                                                int* __restrict__ bpre,
                                                int* __restrict__ offsets,
                                                int nb, int n) {
  __shared__ int lds[256];
  int t = threadIdx.x;
  int v = (t < nb) ? bsum[t] : 0;
  lds[t] = v;
  __syncthreads();
  for (int off = 1; off < 256; off <<= 1) {
    int tv = (t >= off) ? lds[t - off] : 0;
    __syncthreads();
    lds[t] += tv;
    __syncthreads();
  }
  if (t < nb) bpre[t] = lds[t] - v;
  if (t == 0) offsets[n] = lds[255];
}

__global__ __launch_bounds__(256) void scan_add(int* __restrict__ offsets,
                                                int* __restrict__ cursors,
                                                const int* __restrict__ bpre, int n) {
  int i = blockIdx.x * 256 + threadIdx.x;
  if (i < n) {
    int o = offsets[i] + bpre[i >> 8];
    offsets[i] = o;
    cursors[i] = o;
  }
}

__global__ __launch_bounds__(256) void fill_kernel(const int* __restrict__ ei,
                                                   int* __restrict__ cursors,
                                                   int* __restrict__ list,
                                                   int* __restrict__ row, int E) {
  int e = blockIdx.x * 256 + threadIdx.x;
  if (e < E) {
    int d = ei[E + e];
    int pos = atomicAdd(&cursors[d], 1);
    list[pos] = ei[e];
    row[pos] = d;
  }
}

__global__ __launch_bounds__(256) void fill_self(const int* __restrict__ offsets,
                                                 int* __restrict__ list,
                                                 int* __restrict__ row, int n) {
  int i = blockIdx.x * 256 + threadIdx.x;
  if (i < n) {
    int pos = offsets[i + 1] - 1;  // last slot of node i's range
    list[pos] = i;
    row[pos] = i;
  }
}

// ---- packing: tile-linear operand layout ----------------------------------

__global__ __launch_bounds__(256) void pack_x(const float* __restrict__ x,
                                              unsigned short* __restrict__ xpk, int N) {
  int mb = blockIdx.x, ks = blockIdx.y;
  int t = threadIdx.x, l = t & 63, f = t >> 6;
  int row = mb * 64 + f * 16 + (l & 15);
  int kc = ks * 32 + (l >> 4) * 8;
  float v[8];
#pragma unroll
  for (int j = 0; j < 8; ++j) v[j] = 0.f;
  if (row < N) {
    const float* xr = x + (size_t)row * 256 + kc;
#pragma unroll
    for (int j = 0; j < 8; ++j) v[j] = xr[j];
  }
  u16x8 hi, lo;
#pragma unroll
  for (int j = 0; j < 8; ++j) {
    unsigned short h = f2bf(v[j]);
    hi[j] = h; lo[j] = f2bf(v[j] - b2f(h));
  }
  size_t base = (size_t)(mb * 8 + ks) * 8 * 512;
  *(u16x8*)(xpk + base + (size_t)f * 512 + l * 8) = hi;
  *(u16x8*)(xpk + base + (size_t)(4 + f) * 512 + l * 8) = lo;
}

__global__ __launch_bounds__(256) void pack_w1(const float* __restrict__ W,
                                               unsigned short* __restrict__ wpk) {
  int hb = blockIdx.x, ks = blockIdx.y;
  int t = threadIdx.x, l = t & 63, gq = t >> 6;
  for (int g = gq; g < 8; g += 4) {
    int n = hb * 128 + g * 16 + (l & 15);
    int k0 = ks * 32 + (l >> 4) * 8;
    u16x8 hi, lo;
#pragma unroll
    for (int j = 0; j < 8; ++j) {
      float v = W[(size_t)(k0 + j) * 1024 + n];
      unsigned short h = f2bf(v);
      hi[j] = h; lo[j] = f2bf(v - b2f(h));
    }
    size_t base = (size_t)(hb * 8 + ks) * 16 * 512;
    *(u16x8*)(wpk + base + (size_t)g * 512 + l * 8) = hi;
    *(u16x8*)(wpk + base + (size_t)(8 + g) * 512 + l * 8) = lo;
  }
}

__global__ __launch_bounds__(256) void pack_w2(const float* __restrict__ W,
                                               unsigned short* __restrict__ wpk) {
  int ks = blockIdx.x;
  int t = threadIdx.x, l = t & 63, g = t >> 6;
  int n = g * 16 + (l & 15);
  int k0 = ks * 32 + (l >> 4) * 8;
  u16x8 hi, lo;
#pragma unroll
  for (int j = 0; j < 8; ++j) {
    float v = W[(size_t)(k0 + j) * 64 + n];
    unsigned short h = f2bf(v);
    hi[j] = h; lo[j] = f2bf(v - b2f(h));
  }
  size_t base = (size_t)ks * 8 * 512;
  *(u16x8*)(wpk + base + (size_t)g * 512 + l * 8) = hi;
  *(u16x8*)(wpk + base + (size_t)(4 + g) * 512 + l * 8) = lo;
}

// ---- GEMM1 (split-bf16 MFMA) + fused att1 dots ----------------------------

__global__ __launch_bounds__(256) void gemm1_att(
    const unsigned short* __restrict__ xpk, const unsigned short* __restrict__ w1pk,
    const float* __restrict__ asrc, const float* __restrict__ adst,
    unsigned short* __restrict__ h1b, float* __restrict__ as1,
    float* __restrict__ ad1) {
  extern __shared__ char sm[];
  const int t = threadIdx.x, wid = t >> 6, lane = t & 63;
  const int mb = blockIdx.x, hb = blockIdx.y;
  const int m0 = mb * 64;
  const int l15 = lane & 15, l4 = lane >> 4;

  f32x4 acc[4][2] = {};

  auto stage = [&](int buf, int ks) {
    char* base0 = sm + buf * 24576;
    const unsigned short* ax = xpk + (size_t)(mb * 8 + ks) * 8 * 512 + lane * 8;
    for (int i = wid; i < 8; i += 4)
      GLOAD_LDS16(ax + i * 512, base0 + i * 1024);
    const unsigned short* bw = w1pk + (size_t)(hb * 8 + ks) * 16 * 512 + lane * 8;
    for (int i = wid; i < 16; i += 4)
      GLOAD_LDS16(bw + i * 512, base0 + 8192 + i * 1024);
  };

  stage(0, 0);
  __syncthreads();
  int buf = 0;
  for (int step = 0; step < 8; ++step) {
    if (step < 7) stage(buf ^ 1, step + 1);
    const char* b = sm + buf * 24576;
    bf16x8 ah[4], al[4], bh[2], bl[2];
#pragma unroll
    for (int mf = 0; mf < 4; ++mf) {
      ah[mf] = *(const bf16x8*)(b + mf * 1024 + lane * 16);
      al[mf] = *(const bf16x8*)(b + 4096 + mf * 1024 + lane * 16);
    }
#pragma unroll
    for (int nf = 0; nf < 2; ++nf) {
      int g = wid * 2 + nf;
      bh[nf] = *(const bf16x8*)(b + 8192 + g * 1024 + lane * 16);
      bl[nf] = *(const bf16x8*)(b + 16384 + g * 1024 + lane * 16);
    }
#pragma unroll
    for (int mf = 0; mf < 4; ++mf)
#pragma unroll
      for (int nf = 0; nf < 2; ++nf) {
        acc[mf][nf] = __builtin_amdgcn_mfma_f32_16x16x32_bf16(ah[mf], bh[nf], acc[mf][nf], 0, 0, 0);
        acc[mf][nf] = __builtin_amdgcn_mfma_f32_16x16x32_bf16(ah[mf], bl[nf], acc[mf][nf], 0, 0, 0);
        acc[mf][nf] = __builtin_amdgcn_mfma_f32_16x16x32_bf16(al[mf], bh[nf], acc[mf][nf], 0, 0, 0);
      }
    __syncthreads();
    buf ^= 1;
  }

  float* parts_s = (float*)sm;                       // [64][4]
  float* parts_d = (float*)(sm + 1024);              // [64][4]
  unsigned short* ctile = (unsigned short*)(sm + 2048);  // [64][128]
  float as_c[2], ad_c[2];
#pragma unroll
  for (int nf = 0; nf < 2; ++nf) {
    int col = hb * 128 + wid * 32 + nf * 16 + l15;
    as_c[nf] = asrc[col];
    ad_c[nf] = adst[col];
  }
#pragma unroll
  for (int mf = 0; mf < 4; ++mf) {
    float ss[4] = {0.f, 0.f, 0.f, 0.f}, dd[4] = {0.f, 0.f, 0.f, 0.f};
#pragma unroll
    for (int nf = 0; nf < 2; ++nf)
#pragma unroll
      for (int r = 0; r < 4; ++r) {
        ss[r] += acc[mf][nf][r] * as_c[nf];
        dd[r] += acc[mf][nf][r] * ad_c[nf];
      }
#pragma unroll
    for (int r = 0; r < 4; ++r)
      for (int m = 1; m < 16; m <<= 1) {
        ss[r] += __shfl_xor(ss[r], m);
        dd[r] += __shfl_xor(dd[r], m);
      }
    if (l15 == 0) {
#pragma unroll
      for (int r = 0; r < 4; ++r) {
        int row = mf * 16 + l4 * 4 + r;
        parts_s[row * 4 + wid] = ss[r];
        parts_d[row * 4 + wid] = dd[r];
      }
    }
#pragma unroll
    for (int nf = 0; nf < 2; ++nf)
#pragma unroll
      for (int r = 0; r < 4; ++r) {
        int row = mf * 16 + l4 * 4 + r;
        int col = wid * 32 + nf * 16 + l15;
        ctile[row * 128 + col] = f2bf(acc[mf][nf][r]);
      }
  }
  __syncthreads();
  if (t < 64) {
    float s = parts_s[t * 4] + parts_s[t * 4 + 1] + parts_s[t * 4 + 2] + parts_s[t * 4 + 3];
    float d = parts_d[t * 4] + parts_d[t * 4 + 1] + parts_d[t * 4 + 2] + parts_d[t * 4 + 3];
    as1[(size_t)(m0 + t) * 8 + hb] = s;
    ad1[(size_t)(m0 + t) * 8 + hb] = d;
  }
#pragma unroll
  for (int rep = 0; rep < 4; ++rep) {
    int e = rep * 2048 + t * 8;
    int row = e >> 7, col = e & 127;
    bf16x8 v = *(const bf16x8*)(ctile + e);
    *(bf16x8*)(h1b + (size_t)(m0 + row) * 1024 + hb * 128 + col) = v;
  }
}

// ---- edge-parallel e + node-parallel inverse denominators -----------------

__global__ __launch_bounds__(256) void edge_e1(
    const int* __restrict__ list, const int* __restrict__ row,
    const float* __restrict__ as1, const float* __restrict__ ad1,
    float* __restrict__ e1, int T) {
  int tid = blockIdx.x * 256 + threadIdx.x;
  if (tid >= T * 8) return;
  int pos = tid >> 3, h = tid & 7;
  int s = list[pos], d = row[pos];
  e1[tid] = __expf(lrelu(as1[(size_t)s * 8 + h] + ad1[(size_t)d * 8 + h]));
}

__global__ __launch_bounds__(256) void den1_kernel(
    const float* __restrict__ e1, const int* __restrict__ offsets,
    float* __restrict__ invden1, int n) {
  int tid = blockIdx.x * 256 + threadIdx.x;
  if (tid >= n * 8) return;
  int node = tid >> 3, h = tid & 7;
  int beg = offsets[node], end = offsets[node + 1];
  float s = 0.f;
  for (int j = beg; j < end; ++j) s += e1[(size_t)j * 8 + h];
  invden1[tid] = 1.f / (s + 1e-16f);
}

__global__ __launch_bounds__(256) void edge_e2(
    const int* __restrict__ list, const int* __restrict__ row,
    const float* __restrict__ as2, const float* __restrict__ ad2,
    float* __restrict__ e2, int T) {
  int pos = blockIdx.x * 256 + threadIdx.x;
  if (pos >= T) return;
  e2[pos] = __expf(lrelu(as2[list[pos]] + ad2[row[pos]]));
}

__global__ __launch_bounds__(256) void den2_kernel(
    const float* __restrict__ e2, const int* __restrict__ offsets,
    float* __restrict__ invden2, int n) {
  int node = blockIdx.x * 256 + threadIdx.x;
  if (node >= n) return;
  int beg = offsets[node], end = offsets[node + 1];
  float s = 0.f;
  for (int j = beg; j < end; ++j) s += e2[j];
  invden2[node] = 1.f / (s + 1e-16f);
}

// ---- layer-1 gather: one wave per node, barrier-free, no LDS --------------
// Lane l owns channels [l*8, l*8+8) (head l>>4) and [512+l*8, ...) (head 4+(l>>4)).

__global__ __launch_bounds__(256) void agg1_gather(
    const unsigned short* __restrict__ h1b, const float* __restrict__ e1,
    const float* __restrict__ invden1, const int* __restrict__ offsets,
    const int* __restrict__ list, const float* __restrict__ b1,
    unsigned short* __restrict__ o1pk, int n) {
  const int wid = threadIdx.x >> 6, lane = threadIdx.x & 63;
  const int node = blockIdx.x * 4 + wid;
  if (node >= n) return;
  const int beg = offsets[node], end = offsets[node + 1];
  const int h0 = lane >> 4, h1_ = 4 + (lane >> 4);

  float acc0[8] = {}, acc1[8] = {};
  int j = beg;
  for (; j + 2 <= end; j += 2) {
    int sA = list[j], sB = list[j + 1];
    float eA0 = e1[(size_t)j * 8 + h0], eA1 = e1[(size_t)j * 8 + h1_];
    float eB0 = e1[(size_t)(j + 1) * 8 + h0], eB1 = e1[(size_t)(j + 1) * 8 + h1_];
    bf16x8 vA0 = *(const bf16x8*)(h1b + (size_t)sA * 1024 + lane * 8);
    bf16x8 vA1 = *(const bf16x8*)(h1b + (size_t)sA * 1024 + 512 + lane * 8);
    bf16x8 vB0 = *(const bf16x8*)(h1b + (size_t)sB * 1024 + lane * 8);
    bf16x8 vB1 = *(const bf16x8*)(h1b + (size_t)sB * 1024 + 512 + lane * 8);
#pragma unroll
    for (int k = 0; k < 8; ++k) {
      acc0[k] += eA0 * b2f((unsigned short)vA0[k]) + eB0 * b2f((unsigned short)vB0[k]);
      acc1[k] += eA1 * b2f((unsigned short)vA1[k]) + eB1 * b2f((unsigned short)vB1[k]);
    }
  }
  if (j < end) {
    int s = list[j];
    float e0 = e1[(size_t)j * 8 + h0], e1v = e1[(size_t)j * 8 + h1_];
    bf16x8 v0 = *(const bf16x8*)(h1b + (size_t)s * 1024 + lane * 8);
    bf16x8 v1 = *(const bf16x8*)(h1b + (size_t)s * 1024 + 512 + lane * 8);
#pragma unroll
    for (int k = 0; k < 8; ++k) {
      acc0[k] += e0 * b2f((unsigned short)v0[k]);
      acc1[k] += e1v * b2f((unsigned short)v1[k]);
    }
  }

  const float inv0 = invden1[(size_t)node * 8 + h0];
  const float inv1 = invden1[(size_t)node * 8 + h1_];
  u16x8 hiA, loA, hiB, loB;
#pragma unroll
  for (int k = 0; k < 8; ++k) {
    float vA = acc0[k] * inv0 + b1[lane * 8 + k];
    float vB = acc1[k] * inv1 + b1[512 + lane * 8 + k];
    vA = vA > 0.f ? vA : expm1f(vA);
    vB = vB > 0.f ? vB : expm1f(vB);
    unsigned short hA = f2bf(vA), hB = f2bf(vB);
    hiA[k] = hA; loA[k] = f2bf(vA - b2f(hA));
    hiB[k] = hB; loB[k] = f2bf(vB - b2f(hB));
  }
  // packed tile-linear write (gemm2 A operand): tA = lane, tB = 64+lane
  const int mb = node >> 6, f = (node >> 4) & 3, l15 = node & 15;
  {
    int ks = lane >> 2, kc = lane & 3;
    size_t off = (size_t)(mb * 32 + ks) * 4096 + (size_t)f * 512 + (size_t)(kc * 16 + l15) * 8;
    *(u16x8*)(o1pk + off) = hiA;
    *(u16x8*)(o1pk + off + 2048) = loA;
  }
  {
    int ks = 16 + (lane >> 2), kc = lane & 3;
    size_t off = (size_t)(mb * 32 + ks) * 4096 + (size_t)f * 512 + (size_t)(kc * 16 + l15) * 8;
    *(u16x8*)(o1pk + off) = hiB;
    *(u16x8*)(o1pk + off + 2048) = loB;
  }
}

// ---- GEMM2 (split-bf16 MFMA, split-K=4) -----------------------------------

__global__ __launch_bounds__(256) void gemm2_splitk(
    const unsigned short* __restrict__ o1pk, const unsigned short* __restrict__ w2pk,
    float* __restrict__ h2p, int Mpad) {
  extern __shared__ char sm[];
  const int t = threadIdx.x, wid = t >> 6, lane = t & 63;
  const int wr = wid >> 1, wc = wid & 1;
  const int mb = blockIdx.x, sk = blockIdx.y;
  const int m0 = mb * 64;
  const int l15 = lane & 15, l4 = lane >> 4;

  f32x4 acc[2][2] = {};

  auto stage = [&](int buf, int ks) {
    char* base0 = sm + buf * 16384;
    const unsigned short* ax = o1pk + (size_t)(mb * 32 + ks) * 8 * 512 + lane * 8;
    for (int i = wid; i < 8; i += 4)
      GLOAD_LDS16(ax + i * 512, base0 + i * 1024);
    const unsigned short* bw = w2pk + (size_t)ks * 8 * 512 + lane * 8;
    for (int i = wid; i < 8; i += 4)
      GLOAD_LDS16(bw + i * 512, base0 + 8192 + i * 1024);
  };

  stage(0, sk * 8);
  __syncthreads();
  int buf = 0;
  for (int step = 0; step < 8; ++step) {
    if (step < 7) stage(buf ^ 1, sk * 8 + step + 1);
    const char* b = sm + buf * 16384;
    bf16x8 ah[2], al[2], bh[2], bl[2];
#pragma unroll
    for (int mf = 0; mf < 2; ++mf) {
      int f = wr * 2 + mf;
      ah[mf] = *(const bf16x8*)(b + f * 1024 + lane * 16);
      al[mf] = *(const bf16x8*)(b + 4096 + f * 1024 + lane * 16);
    }
#pragma unroll
    for (int nf = 0; nf < 2; ++nf) {
      int g = wc * 2 + nf;
      bh[nf] = *(const bf16x8*)(b + 8192 + g * 1024 + lane * 16);
      bl[nf] = *(const bf16x8*)(b + 12288 + g * 1024 + lane * 16);
    }
#pragma unroll
    for (int mf = 0; mf < 2; ++mf)
#pragma unroll
      for (int nf = 0; nf < 2; ++nf) {
        acc[mf][nf] = __builtin_amdgcn_mfma_f32_16x16x32_bf16(ah[mf], bh[nf], acc[mf][nf], 0, 0, 0);
        acc[mf][nf] = __builtin_amdgcn_mfma_f32_16x16x32_bf16(ah[mf], bl[nf], acc[mf][nf], 0, 0, 0);
        acc[mf][nf] = __builtin_amdgcn_mfma_f32_16x16x32_bf16(al[mf], bh[nf], acc[mf][nf], 0, 0, 0);
      }
    __syncthreads();
    buf ^= 1;
  }

#pragma unroll
  for (int mf = 0; mf < 2; ++mf)
#pragma unroll
    for (int nf = 0; nf < 2; ++nf)
#pragma unroll
      for (int r = 0; r < 4; ++r) {
        int row = wr * 32 + mf * 16 + l4 * 4 + r;
        int col = wc * 32 + nf * 16 + l15;
        h2p[((size_t)sk * Mpad + m0 + row) * 64 + col] = acc[mf][nf][r];
      }
}

// ---- reduce split-K partials + att2 dots ----------------------------------

__global__ __launch_bounds__(256) void reduce_att2(
    const float* __restrict__ h2p, const float* __restrict__ asrc,
    const float* __restrict__ adst, float* __restrict__ h2,
    float* __restrict__ as2, float* __restrict__ ad2, int Mpad, int n) {
  int w = threadIdx.x >> 6, lane = threadIdx.x & 63;
  int row = blockIdx.x * 4 + w;
  if (row >= n) return;
  float s = 0.f;
#pragma unroll
  for (int sk = 0; sk < 4; ++sk) s += h2p[((size_t)sk * Mpad + row) * 64 + lane];
  h2[(size_t)row * 64 + lane] = s;
  float ds = s * asrc[lane], dd = s * adst[lane];
  for (int o = 32; o; o >>= 1) { ds += __shfl_xor(ds, o); dd += __shfl_xor(dd, o); }
  if (lane == 0) { as2[row] = ds; ad2[row] = dd; }
}

// ---- layer-2 gather: one wave per node, barrier-free ----------------------

__global__ __launch_bounds__(256) void agg2_gather(
    const float* __restrict__ h2, const float* __restrict__ e2,
    const float* __restrict__ invden2, const int* __restrict__ offsets,
    const int* __restrict__ list, const float* __restrict__ b2,
    float* __restrict__ out, int n) {
  const int wid = threadIdx.x >> 6, lane = threadIdx.x & 63;
  const int node = blockIdx.x * 4 + wid;
  if (node >= n) return;
  const int beg = offsets[node], end = offsets[node + 1];
  const int cb = (lane & 15) * 4;  // 4 channels per lane
  const int jo = lane >> 4;        // row-in-quad

  float4 acc = make_float4(0.f, 0.f, 0.f, 0.f);
  for (int j = beg + jo; j < end; j += 4) {
    float e = e2[j];
    int s = list[j];
    float4 v = *(const float4*)&h2[(size_t)s * 64 + cb];
    acc.x += e * v.x; acc.y += e * v.y; acc.z += e * v.z; acc.w += e * v.w;
  }
  acc.x += __shfl_xor(acc.x, 16); acc.y += __shfl_xor(acc.y, 16);
  acc.z += __shfl_xor(acc.z, 16); acc.w += __shfl_xor(acc.w, 16);
  acc.x += __shfl_xor(acc.x, 32); acc.y += __shfl_xor(acc.y, 32);
  acc.z += __shfl_xor(acc.z, 32); acc.w += __shfl_xor(acc.w, 32);
  if (jo == 0) {
    float inv = invden2[node];
    float4 r;
    r.x = acc.x * inv + b2[cb];
    r.y = acc.y * inv + b2[cb + 1];
    r.z = acc.z * inv + b2[cb + 2];
    r.w = acc.w * inv + b2[cb + 3];
    *(float4*)&out[(size_t)node * 64 + cb] = r;
  }
}

// ---------------------------------------------------------------------------

extern "C" void kernel_launch(void* const* d_in, const int* in_sizes, int n_in,
                              void* d_out, int out_size, void* d_ws, size_t ws_size,
                              hipStream_t stream) {
  const float* x     = (const float*)d_in[0];
  const int*   ei    = (const int*)d_in[1];
  const float* W1    = (const float*)d_in[2];
  const float* asrc1 = (const float*)d_in[3];
  const float* adst1 = (const float*)d_in[4];
  const float* b1    = (const float*)d_in[5];
  const float* W2    = (const float*)d_in[6];
  const float* asrc2 = (const float*)d_in[7];
  const float* adst2 = (const float*)d_in[8];
  const float* b2    = (const float*)d_in[9];
  float* out = (float*)d_out;

  const int N = in_sizes[0] / 256;
  const int E = in_sizes[1] / 2;
  const int T = E + N;  // edges + self loops
  const int MB1 = (N + 63) / 64;
  const int Mpad = MB1 * 64;
  const int NB = (N + 255) / 256;

  char* p = (char*)d_ws;
  auto bump = [&](size_t bytes) {
    char* r = p;
    p += (bytes + 255) & ~(size_t)255;
    return r;
  };
  int* counts  = (int*)bump((size_t)N * 4);
  int* offsets = (int*)bump((size_t)(N + 1) * 4);
  int* cursors = (int*)bump((size_t)N * 4);
  int* bsum    = (int*)bump((size_t)NB * 4);
  int* bpre    = (int*)bump((size_t)NB * 4);
  int* list    = (int*)bump((size_t)T * 4);
  int* row     = (int*)bump((size_t)T * 4);
  unsigned short* xpk  = (unsigned short*)bump((size_t)Mpad * 512 * 2);   // hi+lo
  unsigned short* w1pk = (unsigned short*)bump((size_t)8 * 8 * 16 * 512 * 2);
  unsigned short* h1b  = (unsigned short*)bump((size_t)Mpad * 1024 * 2);
  float* as1           = (float*)bump((size_t)Mpad * 8 * 4);
  float* ad1           = (float*)bump((size_t)Mpad * 8 * 4);
  float* e1            = (float*)bump((size_t)T * 8 * 4);
  float* invden1       = (float*)bump((size_t)N * 8 * 4);
  unsigned short* o1pk = (unsigned short*)bump((size_t)Mpad * 2048 * 2);  // hi+lo
  unsigned short* w2pk = (unsigned short*)bump((size_t)32 * 8 * 512 * 2);
  float* as2           = (float*)bump((size_t)Mpad * 4);
  float* ad2           = (float*)bump((size_t)Mpad * 4);
  float* e2            = (float*)bump((size_t)T * 4);
  float* invden2       = (float*)bump((size_t)N * 4);
  // aliases (safe: single-stream ordering; last reader precedes first writer)
  float* h2p = (float*)h1b;   // 4*Mpad*64*4B = Mpad*1KB <= Mpad*2KB
  float* h2  = (float*)xpk;   // Mpad*64*4B = Mpad*256B <= Mpad*1KB

  // CSR (self loops appended as last slot per node)
  hipMemsetAsync(counts, 0, (size_t)N * 4, stream);
  count_kernel<<<(E + 255) / 256, 256, 0, stream>>>(ei, counts, E);
  scan_blk<<<NB, 256, 0, stream>>>(counts, offsets, bsum, N);
  scan_top<<<1, 256, 0, stream>>>(bsum, bpre, offsets, NB, N);
  scan_add<<<NB, 256, 0, stream>>>(offsets, cursors, bpre, N);
  fill_kernel<<<(E + 255) / 256, 256, 0, stream>>>(ei, cursors, list, row, E);
  fill_self<<<NB, 256, 0, stream>>>(offsets, list, row, N);

  // packing
  pack_x<<<dim3(MB1, 8), 256, 0, stream>>>(x, xpk, N);
  pack_w1<<<dim3(8, 8), 256, 0, stream>>>(W1, w1pk);
  pack_w2<<<32, 256, 0, stream>>>(W2, w2pk);

  // layer 1
  gemm1_att<<<dim3(MB1, 8), 256, 49152, stream>>>(xpk, w1pk, asrc1, adst1, h1b, as1, ad1);
  edge_e1<<<(T * 8 + 255) / 256, 256, 0, stream>>>(list, row, as1, ad1, e1, T);
  den1_kernel<<<(N * 8 + 255) / 256, 256, 0, stream>>>(e1, offsets, invden1, N);
  agg1_gather<<<(N + 3) / 4, 256, 0, stream>>>(h1b, e1, invden1, offsets, list, b1, o1pk, N);

  // layer 2
  gemm2_splitk<<<dim3(MB1, 4), 256, 32768, stream>>>(o1pk, w2pk, h2p, Mpad);
  reduce_att2<<<(N + 3) / 4, 256, 0, stream>>>(h2p, asrc2, adst2, h2, as2, ad2, Mpad, N);
  edge_e2<<<(T + 255) / 256, 256, 0, stream>>>(list, row, as2, ad2, e2, T);
  den2_kernel<<<NB, 256, 0, stream>>>(e2, offsets, invden2, N);
  agg2_gather<<<(N + 3) / 4, 256, 0, stream>>>(h2, e2, invden2, offsets, list, b2, out, N);
}

// Round 6
// 164.503 us; speedup vs baseline: 1.2341x; 1.2341x over previous
//
#include <hip/hip_runtime.h>
#include <cmath>

// ---------------------------------------------------------------------------
// 2-layer GAT, N=10000, E=160000(+self loops in CSR), F_IN=256 ->
// [8x128 concat]=1024 -> ELU -> [1x64]. Split-bf16 MFMA GEMMs (3-term),
// tile-linear packed operands, split-K GEMM2. Aggregation: fused-e one-wave-
// per-node gather with deferred normalization; LDS-staged coalesced packed
// output. 10 dispatches total.
// ---------------------------------------------------------------------------

typedef short bf16x8 __attribute__((ext_vector_type(8)));
typedef float f32x4 __attribute__((ext_vector_type(4)));
typedef unsigned short u16x8 __attribute__((ext_vector_type(8)));

__device__ __forceinline__ float lrelu(float x) { return x > 0.f ? x : 0.2f * x; }
__device__ __forceinline__ float b2f(unsigned short h) {
  return __uint_as_float(((unsigned)h) << 16);
}
__device__ __forceinline__ unsigned short f2bf(float f) {
  unsigned u = __float_as_uint(f);
  u += 0x7FFFu + ((u >> 16) & 1u);
  return (unsigned short)(u >> 16);
}

#define GLOAD_LDS16(gsrc, ldst)                                              \
  __builtin_amdgcn_global_load_lds(                                          \
      (const __attribute__((address_space(1))) unsigned int*)(gsrc),         \
      (__attribute__((address_space(3))) unsigned int*)(ldst), 16, 0, 0)

// ---- fused prep: count (atomics) + pack_x + pack_w1 + pack_w2 -------------
// Subtile = 16(rows) x 32(k) bf16 = 1024B, lane-linear: lane l supplies
// (row = l&15, kchunk = l>>4), 16B per lane.

__global__ __launch_bounds__(256) void prep_fused(
    const int* __restrict__ ei, int* __restrict__ counts, int E,
    const float* __restrict__ x, unsigned short* __restrict__ xpk, int N, int MB1,
    const float* __restrict__ W1, unsigned short* __restrict__ w1pk,
    const float* __restrict__ W2, unsigned short* __restrict__ w2pk) {
  const int countB = (E + 255) / 256;
  const int pxB = MB1 * 8;
  int bid = blockIdx.x;
  int t = threadIdx.x;

  if (bid < countB) {  // ---- degree count
    int e = bid * 256 + t;
    if (e < E) atomicAdd(&counts[ei[E + e]], 1);
    return;
  }
  bid -= countB;
  if (bid < pxB) {  // ---- pack x (hi/lo split, zero-padded rows)
    int mb = bid >> 3, ks = bid & 7;
    int l = t & 63, f = t >> 6;
    int row = mb * 64 + f * 16 + (l & 15);
    int kc = ks * 32 + (l >> 4) * 8;
    float v[8];
#pragma unroll
    for (int j = 0; j < 8; ++j) v[j] = 0.f;
    if (row < N) {
      const float* xr = x + (size_t)row * 256 + kc;
#pragma unroll
      for (int j = 0; j < 8; ++j) v[j] = xr[j];
    }
    u16x8 hi, lo;
#pragma unroll
    for (int j = 0; j < 8; ++j) {
      unsigned short h = f2bf(v[j]);
      hi[j] = h; lo[j] = f2bf(v[j] - b2f(h));
    }
    size_t base = (size_t)(mb * 8 + ks) * 8 * 512;
    *(u16x8*)(xpk + base + (size_t)f * 512 + l * 8) = hi;
    *(u16x8*)(xpk + base + (size_t)(4 + f) * 512 + l * 8) = lo;
    return;
  }
  bid -= pxB;
  if (bid < 64) {  // ---- pack W1^T
    int hb = bid >> 3, ks = bid & 7;
    int l = t & 63, gq = t >> 6;
    for (int g = gq; g < 8; g += 4) {
      int n = hb * 128 + g * 16 + (l & 15);
      int k0 = ks * 32 + (l >> 4) * 8;
      u16x8 hi, lo;
#pragma unroll
      for (int j = 0; j < 8; ++j) {
        float v = W1[(size_t)(k0 + j) * 1024 + n];
        unsigned short h = f2bf(v);
        hi[j] = h; lo[j] = f2bf(v - b2f(h));
      }
      size_t base = (size_t)(hb * 8 + ks) * 16 * 512;
      *(u16x8*)(w1pk + base + (size_t)g * 512 + l * 8) = hi;
      *(u16x8*)(w1pk + base + (size_t)(8 + g) * 512 + l * 8) = lo;
    }
    return;
  }
  bid -= 64;
  {  // ---- pack W2^T (32 blocks)
    int ks = bid;
    int l = t & 63, g = t >> 6;
    int n = g * 16 + (l & 15);
    int k0 = ks * 32 + (l >> 4) * 8;
    u16x8 hi, lo;
#pragma unroll
    for (int j = 0; j < 8; ++j) {
      float v = W2[(size_t)(k0 + j) * 64 + n];
      unsigned short h = f2bf(v);
      hi[j] = h; lo[j] = f2bf(v - b2f(h));
    }
    size_t base = (size_t)ks * 8 * 512;
    *(u16x8*)(w2pk + base + (size_t)g * 512 + l * 8) = hi;
    *(u16x8*)(w2pk + base + (size_t)(4 + g) * 512 + l * 8) = lo;
  }
}

// ---- CSR scan (v[i] = counts[i] + 1 for self loop) ------------------------

__global__ __launch_bounds__(256) void scan_blk(const int* __restrict__ counts,
                                                int* __restrict__ offsets,
                                                int* __restrict__ bsum, int n) {
  __shared__ int lds[256];
  int b = blockIdx.x, t = threadIdx.x, i = b * 256 + t;
  int v = (i < n) ? counts[i] + 1 : 0;
  lds[t] = v;
  __syncthreads();
  for (int off = 1; off < 256; off <<= 1) {
    int tv = (t >= off) ? lds[t - off] : 0;
    __syncthreads();
    lds[t] += tv;
    __syncthreads();
  }
  if (i < n) offsets[i] = lds[t] - v;
  if (t == 255) bsum[b] = lds[255];
}

__global__ __launch_bounds__(256) void scan_apply(int* __restrict__ offsets,
                                                  int* __restrict__ cursors,
                                                  const int* __restrict__ bsum,
                                                  int nb, int n) {
  __shared__ int pre_s;
  int b = blockIdx.x, t = threadIdx.x;
  if (t == 0) {
    int s = 0;
    for (int i = 0; i < b; ++i) s += bsum[i];
    pre_s = s;
    if (b == nb - 1) {
      int tot = s;
      for (int i = b; i < nb; ++i) tot += bsum[i];
      offsets[n] = tot;
    }
  }
  __syncthreads();
  int i = b * 256 + t;
  if (i < n) {
    int o = offsets[i] + pre_s;
    offsets[i] = o;
    cursors[i] = o;
  }
}

__global__ __launch_bounds__(256) void fill_all(const int* __restrict__ ei,
                                                int* __restrict__ cursors,
                                                const int* __restrict__ offsets,
                                                int* __restrict__ list,
                                                int E, int n) {
  int tid = blockIdx.x * 256 + threadIdx.x;
  if (tid < E) {
    int d = ei[E + tid];
    int pos = atomicAdd(&cursors[d], 1);
    list[pos] = ei[tid];
  } else if (tid < E + n) {
    int i = tid - E;
    list[offsets[i + 1] - 1] = i;  // self loop in last slot
  }
}

// ---- GEMM1 (split-bf16 MFMA) + fused att1 dots ----------------------------

__global__ __launch_bounds__(256) void gemm1_att(
    const unsigned short* __restrict__ xpk, const unsigned short* __restrict__ w1pk,
    const float* __restrict__ asrc, const float* __restrict__ adst,
    unsigned short* __restrict__ h1b, float* __restrict__ as1,
    float* __restrict__ ad1) {
  extern __shared__ char sm[];
  const int t = threadIdx.x, wid = t >> 6, lane = t & 63;
  const int mb = blockIdx.x, hb = blockIdx.y;
  const int m0 = mb * 64;
  const int l15 = lane & 15, l4 = lane >> 4;

  f32x4 acc[4][2] = {};

  auto stage = [&](int buf, int ks) {
    char* base0 = sm + buf * 24576;
    const unsigned short* ax = xpk + (size_t)(mb * 8 + ks) * 8 * 512 + lane * 8;
    for (int i = wid; i < 8; i += 4)
      GLOAD_LDS16(ax + i * 512, base0 + i * 1024);
    const unsigned short* bw = w1pk + (size_t)(hb * 8 + ks) * 16 * 512 + lane * 8;
    for (int i = wid; i < 16; i += 4)
      GLOAD_LDS16(bw + i * 512, base0 + 8192 + i * 1024);
  };

  stage(0, 0);
  __syncthreads();
  int buf = 0;
  for (int step = 0; step < 8; ++step) {
    if (step < 7) stage(buf ^ 1, step + 1);
    const char* b = sm + buf * 24576;
    bf16x8 ah[4], al[4], bh[2], bl[2];
#pragma unroll
    for (int mf = 0; mf < 4; ++mf) {
      ah[mf] = *(const bf16x8*)(b + mf * 1024 + lane * 16);
      al[mf] = *(const bf16x8*)(b + 4096 + mf * 1024 + lane * 16);
    }
#pragma unroll
    for (int nf = 0; nf < 2; ++nf) {
      int g = wid * 2 + nf;
      bh[nf] = *(const bf16x8*)(b + 8192 + g * 1024 + lane * 16);
      bl[nf] = *(const bf16x8*)(b + 16384 + g * 1024 + lane * 16);
    }
#pragma unroll
    for (int mf = 0; mf < 4; ++mf)
#pragma unroll
      for (int nf = 0; nf < 2; ++nf) {
        acc[mf][nf] = __builtin_amdgcn_mfma_f32_16x16x32_bf16(ah[mf], bh[nf], acc[mf][nf], 0, 0, 0);
        acc[mf][nf] = __builtin_amdgcn_mfma_f32_16x16x32_bf16(ah[mf], bl[nf], acc[mf][nf], 0, 0, 0);
        acc[mf][nf] = __builtin_amdgcn_mfma_f32_16x16x32_bf16(al[mf], bh[nf], acc[mf][nf], 0, 0, 0);
      }
    __syncthreads();
    buf ^= 1;
  }

  float* parts_s = (float*)sm;                       // [64][4]
  float* parts_d = (float*)(sm + 1024);              // [64][4]
  unsigned short* ctile = (unsigned short*)(sm + 2048);  // [64][128]
  float as_c[2], ad_c[2];
#pragma unroll
  for (int nf = 0; nf < 2; ++nf) {
    int col = hb * 128 + wid * 32 + nf * 16 + l15;
    as_c[nf] = asrc[col];
    ad_c[nf] = adst[col];
  }
#pragma unroll
  for (int mf = 0; mf < 4; ++mf) {
    float ss[4] = {0.f, 0.f, 0.f, 0.f}, dd[4] = {0.f, 0.f, 0.f, 0.f};
#pragma unroll
    for (int nf = 0; nf < 2; ++nf)
#pragma unroll
      for (int r = 0; r < 4; ++r) {
        ss[r] += acc[mf][nf][r] * as_c[nf];
        dd[r] += acc[mf][nf][r] * ad_c[nf];
      }
#pragma unroll
    for (int r = 0; r < 4; ++r)
      for (int m = 1; m < 16; m <<= 1) {
        ss[r] += __shfl_xor(ss[r], m);
        dd[r] += __shfl_xor(dd[r], m);
      }
    if (l15 == 0) {
#pragma unroll
      for (int r = 0; r < 4; ++r) {
        int row = mf * 16 + l4 * 4 + r;
        parts_s[row * 4 + wid] = ss[r];
        parts_d[row * 4 + wid] = dd[r];
      }
    }
#pragma unroll
    for (int nf = 0; nf < 2; ++nf)
#pragma unroll
      for (int r = 0; r < 4; ++r) {
        int row = mf * 16 + l4 * 4 + r;
        int col = wid * 32 + nf * 16 + l15;
        ctile[row * 128 + col] = f2bf(acc[mf][nf][r]);
      }
  }
  __syncthreads();
  if (t < 64) {
    float s = parts_s[t * 4] + parts_s[t * 4 + 1] + parts_s[t * 4 + 2] + parts_s[t * 4 + 3];
    float d = parts_d[t * 4] + parts_d[t * 4 + 1] + parts_d[t * 4 + 2] + parts_d[t * 4 + 3];
    as1[(size_t)(m0 + t) * 8 + hb] = s;
    ad1[(size_t)(m0 + t) * 8 + hb] = d;
  }
#pragma unroll
  for (int rep = 0; rep < 4; ++rep) {
    int e = rep * 2048 + t * 8;
    int row = e >> 7, col = e & 127;
    bf16x8 v = *(const bf16x8*)(ctile + e);
    *(bf16x8*)(h1b + (size_t)(m0 + row) * 1024 + hb * 128 + col) = v;
  }
}

// ---- layer-1 gather: one wave per node, fused e+den, LDS-staged output ----
// Block = 512 thr = 8 waves = 8 nodes. Lane l owns channels [l*8,l*8+8)
// (head l>>4) and [512+l*8,...) (head 4+(l>>4)). Packed o1pk image staged in
// 32KB LDS (XOR swizzle (ks&7)<<4), written out as full 128B lines.

__global__ __launch_bounds__(512) void agg1_gather8(
    const unsigned short* __restrict__ h1b, const float* __restrict__ as1,
    const float* __restrict__ ad1, const int* __restrict__ offsets,
    const int* __restrict__ list, const float* __restrict__ b1,
    unsigned short* __restrict__ o1pk, int n) {
  __shared__ unsigned short stg[16384];  // 32 KB
  const int t = threadIdx.x, w = t >> 6, lane = t & 63;
  const int node = blockIdx.x * 8 + w;
  const int h0 = lane >> 4, h1_ = 4 + (lane >> 4);

  if (node < n) {
    const int beg = offsets[node], end = offsets[node + 1];
    const float ad0 = ad1[(size_t)node * 8 + h0];
    const float ad4 = ad1[(size_t)node * 8 + h1_];

    float acc0[8] = {}, acc1[8] = {};
    float den0 = 0.f, den4 = 0.f;
    int j = beg;
    for (; j + 2 <= end; j += 2) {
      int sA = list[j], sB = list[j + 1];
      float eA0 = __expf(lrelu(as1[(size_t)sA * 8 + h0] + ad0));
      float eA4 = __expf(lrelu(as1[(size_t)sA * 8 + h1_] + ad4));
      float eB0 = __expf(lrelu(as1[(size_t)sB * 8 + h0] + ad0));
      float eB4 = __expf(lrelu(as1[(size_t)sB * 8 + h1_] + ad4));
      den0 += eA0 + eB0; den4 += eA4 + eB4;
      bf16x8 vA0 = *(const bf16x8*)(h1b + (size_t)sA * 1024 + lane * 8);
      bf16x8 vA1 = *(const bf16x8*)(h1b + (size_t)sA * 1024 + 512 + lane * 8);
      bf16x8 vB0 = *(const bf16x8*)(h1b + (size_t)sB * 1024 + lane * 8);
      bf16x8 vB1 = *(const bf16x8*)(h1b + (size_t)sB * 1024 + 512 + lane * 8);
#pragma unroll
      for (int k = 0; k < 8; ++k) {
        acc0[k] += eA0 * b2f((unsigned short)vA0[k]) + eB0 * b2f((unsigned short)vB0[k]);
        acc1[k] += eA4 * b2f((unsigned short)vA1[k]) + eB4 * b2f((unsigned short)vB1[k]);
      }
    }
    if (j < end) {
      int s = list[j];
      float e0 = __expf(lrelu(as1[(size_t)s * 8 + h0] + ad0));
      float e4 = __expf(lrelu(as1[(size_t)s * 8 + h1_] + ad4));
      den0 += e0; den4 += e4;
      bf16x8 v0 = *(const bf16x8*)(h1b + (size_t)s * 1024 + lane * 8);
      bf16x8 v1 = *(const bf16x8*)(h1b + (size_t)s * 1024 + 512 + lane * 8);
#pragma unroll
      for (int k = 0; k < 8; ++k) {
        acc0[k] += e0 * b2f((unsigned short)v0[k]);
        acc1[k] += e4 * b2f((unsigned short)v1[k]);
      }
    }

    const float inv0 = 1.f / (den0 + 1e-16f);
    const float inv4 = 1.f / (den4 + 1e-16f);
    u16x8 hiA, loA, hiB, loB;
#pragma unroll
    for (int k = 0; k < 8; ++k) {
      float vA = acc0[k] * inv0 + b1[lane * 8 + k];
      float vB = acc1[k] * inv4 + b1[512 + lane * 8 + k];
      vA = vA > 0.f ? vA : expm1f(vA);
      vB = vB > 0.f ? vB : expm1f(vB);
      unsigned short hA = f2bf(vA), hB = f2bf(vB);
      hiA[k] = hA; loA[k] = f2bf(vA - b2f(hA));
      hiB[k] = hB; loB[k] = f2bf(vB - b2f(hB));
    }
    // stage into LDS packed image: addr = ks*1024 + half*512 + kc*128 + w*16
    // bytes, XOR-swizzled by ((ks&7)<<4).
    const int q = lane >> 2, kc = lane & 3;
    {
      int a = q * 1024 + kc * 128 + w * 16;
      *(u16x8*)((char*)stg + (a ^ ((q & 7) << 4))) = hiA;
      a += 512;
      *(u16x8*)((char*)stg + (a ^ ((q & 7) << 4))) = loA;
    }
    {
      int ks = 16 + q;
      int a = ks * 1024 + kc * 128 + w * 16;
      *(u16x8*)((char*)stg + (a ^ ((ks & 7) << 4))) = hiB;
      a += 512;
      *(u16x8*)((char*)stg + (a ^ ((ks & 7) << 4))) = loB;
    }
  }
  __syncthreads();
  // coalesced copy-out: 4 iters x 512 thr x 16B = 32KB, full 128B lines.
  const int blk = blockIdx.x;
  const int mb = blk >> 3, f = (blk >> 1) & 3, l15b = (blk & 1) * 8;
#pragma unroll
  for (int it = 0; it < 4; ++it) {
    int a = it * 8192 + t * 16;
    int ks = a >> 10, half = (a >> 9) & 1, kcc = (a >> 7) & 3, ww = (a >> 4) & 7;
    u16x8 v = *(const u16x8*)((const char*)stg + (a ^ ((ks & 7) << 4)));
    size_t g = (size_t)(mb * 32 + ks) * 4096 + half * 2048 + (size_t)f * 512 +
               (size_t)(kcc * 16 + l15b + ww) * 8;
    *(u16x8*)(o1pk + g) = v;
  }
}

// ---- GEMM2 (split-bf16 MFMA, split-K=4) -----------------------------------

__global__ __launch_bounds__(256) void gemm2_splitk(
    const unsigned short* __restrict__ o1pk, const unsigned short* __restrict__ w2pk,
    float* __restrict__ h2p, int Mpad) {
  extern __shared__ char sm[];
  const int t = threadIdx.x, wid = t >> 6, lane = t & 63;
  const int wr = wid >> 1, wc = wid & 1;
  const int mb = blockIdx.x, sk = blockIdx.y;
  const int m0 = mb * 64;
  const int l15 = lane & 15, l4 = lane >> 4;

  f32x4 acc[2][2] = {};

  auto stage = [&](int buf, int ks) {
    char* base0 = sm + buf * 16384;
    const unsigned short* ax = o1pk + (size_t)(mb * 32 + ks) * 8 * 512 + lane * 8;
    for (int i = wid; i < 8; i += 4)
      GLOAD_LDS16(ax + i * 512, base0 + i * 1024);
    const unsigned short* bw = w2pk + (size_t)ks * 8 * 512 + lane * 8;
    for (int i = wid; i < 8; i += 4)
      GLOAD_LDS16(bw + i * 512, base0 + 8192 + i * 1024);
  };

  stage(0, sk * 8);
  __syncthreads();
  int buf = 0;
  for (int step = 0; step < 8; ++step) {
    if (step < 7) stage(buf ^ 1, sk * 8 + step + 1);
    const char* b = sm + buf * 16384;
    bf16x8 ah[2], al[2], bh[2], bl[2];
#pragma unroll
    for (int mf = 0; mf < 2; ++mf) {
      int f = wr * 2 + mf;
      ah[mf] = *(const bf16x8*)(b + f * 1024 + lane * 16);
      al[mf] = *(const bf16x8*)(b + 4096 + f * 1024 + lane * 16);
    }
#pragma unroll
    for (int nf = 0; nf < 2; ++nf) {
      int g = wc * 2 + nf;
      bh[nf] = *(const bf16x8*)(b + 8192 + g * 1024 + lane * 16);
      bl[nf] = *(const bf16x8*)(b + 12288 + g * 1024 + lane * 16);
    }
#pragma unroll
    for (int mf = 0; mf < 2; ++mf)
#pragma unroll
      for (int nf = 0; nf < 2; ++nf) {
        acc[mf][nf] = __builtin_amdgcn_mfma_f32_16x16x32_bf16(ah[mf], bh[nf], acc[mf][nf], 0, 0, 0);
        acc[mf][nf] = __builtin_amdgcn_mfma_f32_16x16x32_bf16(ah[mf], bl[nf], acc[mf][nf], 0, 0, 0);
        acc[mf][nf] = __builtin_amdgcn_mfma_f32_16x16x32_bf16(al[mf], bh[nf], acc[mf][nf], 0, 0, 0);
      }
    __syncthreads();
    buf ^= 1;
  }

#pragma unroll
  for (int mf = 0; mf < 2; ++mf)
#pragma unroll
    for (int nf = 0; nf < 2; ++nf)
#pragma unroll
      for (int r = 0; r < 4; ++r) {
        int row = wr * 32 + mf * 16 + l4 * 4 + r;
        int col = wc * 32 + nf * 16 + l15;
        h2p[((size_t)sk * Mpad + m0 + row) * 64 + col] = acc[mf][nf][r];
      }
}

// ---- reduce split-K partials + att2 dots ----------------------------------

__global__ __launch_bounds__(256) void reduce_att2(
    const float* __restrict__ h2p, const float* __restrict__ asrc,
    const float* __restrict__ adst, float* __restrict__ h2,
    float* __restrict__ as2, float* __restrict__ ad2, int Mpad, int n) {
  int w = threadIdx.x >> 6, lane = threadIdx.x & 63;
  int row = blockIdx.x * 4 + w;
  if (row >= n) return;
  float s = 0.f;
#pragma unroll
  for (int sk = 0; sk < 4; ++sk) s += h2p[((size_t)sk * Mpad + row) * 64 + lane];
  h2[(size_t)row * 64 + lane] = s;
  float ds = s * asrc[lane], dd = s * adst[lane];
  for (int o = 32; o; o >>= 1) { ds += __shfl_xor(ds, o); dd += __shfl_xor(dd, o); }
  if (lane == 0) { as2[row] = ds; ad2[row] = dd; }
}

// ---- layer-2 gather: one wave per node, fused e+den -----------------------

__global__ __launch_bounds__(256) void agg2_gather(
    const float* __restrict__ h2, const float* __restrict__ as2,
    const float* __restrict__ ad2, const int* __restrict__ offsets,
    const int* __restrict__ list, const float* __restrict__ b2,
    float* __restrict__ out, int n) {
  const int wid = threadIdx.x >> 6, lane = threadIdx.x & 63;
  const int node = blockIdx.x * 4 + wid;
  if (node >= n) return;
  const int beg = offsets[node], end = offsets[node + 1];
  const float ad = ad2[node];
  const int cb = (lane & 15) * 4;  // 4 channels per lane
  const int jo = lane >> 4;        // row-in-quad

  float4 acc = make_float4(0.f, 0.f, 0.f, 0.f);
  float den = 0.f;
  for (int j = beg + jo; j < end; j += 4) {
    int s = list[j];
    float e = __expf(lrelu(as2[s] + ad));
    den += e;
    float4 v = *(const float4*)&h2[(size_t)s * 64 + cb];
    acc.x += e * v.x; acc.y += e * v.y; acc.z += e * v.z; acc.w += e * v.w;
  }
  acc.x += __shfl_xor(acc.x, 16); acc.y += __shfl_xor(acc.y, 16);
  acc.z += __shfl_xor(acc.z, 16); acc.w += __shfl_xor(acc.w, 16);
  den += __shfl_xor(den, 16);
  acc.x += __shfl_xor(acc.x, 32); acc.y += __shfl_xor(acc.y, 32);
  acc.z += __shfl_xor(acc.z, 32); acc.w += __shfl_xor(acc.w, 32);
  den += __shfl_xor(den, 32);
  if (jo == 0) {
    float inv = 1.f / (den + 1e-16f);
    float4 r;
    r.x = acc.x * inv + b2[cb];
    r.y = acc.y * inv + b2[cb + 1];
    r.z = acc.z * inv + b2[cb + 2];
    r.w = acc.w * inv + b2[cb + 3];
    *(float4*)&out[(size_t)node * 64 + cb] = r;
  }
}

// ---------------------------------------------------------------------------

extern "C" void kernel_launch(void* const* d_in, const int* in_sizes, int n_in,
                              void* d_out, int out_size, void* d_ws, size_t ws_size,
                              hipStream_t stream) {
  const float* x     = (const float*)d_in[0];
  const int*   ei    = (const int*)d_in[1];
  const float* W1    = (const float*)d_in[2];
  const float* asrc1 = (const float*)d_in[3];
  const float* adst1 = (const float*)d_in[4];
  const float* b1    = (const float*)d_in[5];
  const float* W2    = (const float*)d_in[6];
  const float* asrc2 = (const float*)d_in[7];
  const float* adst2 = (const float*)d_in[8];
  const float* b2    = (const float*)d_in[9];
  float* out = (float*)d_out;

  const int N = in_sizes[0] / 256;
  const int E = in_sizes[1] / 2;
  const int T = E + N;  // edges + self loops
  const int MB1 = (N + 63) / 64;
  const int Mpad = MB1 * 64;
  const int NB = (N + 255) / 256;

  char* p = (char*)d_ws;
  auto bump = [&](size_t bytes) {
    char* r = p;
    p += (bytes + 255) & ~(size_t)255;
    return r;
  };
  int* counts  = (int*)bump((size_t)N * 4);
  int* offsets = (int*)bump((size_t)(N + 1) * 4);
  int* cursors = (int*)bump((size_t)N * 4);
  int* bsum    = (int*)bump((size_t)NB * 4);
  int* list    = (int*)bump((size_t)T * 4);
  unsigned short* xpk  = (unsigned short*)bump((size_t)Mpad * 512 * 2);   // hi+lo
  unsigned short* w1pk = (unsigned short*)bump((size_t)8 * 8 * 16 * 512 * 2);
  unsigned short* h1b  = (unsigned short*)bump((size_t)Mpad * 1024 * 2);
  float* as1           = (float*)bump((size_t)Mpad * 8 * 4);
  float* ad1           = (float*)bump((size_t)Mpad * 8 * 4);
  unsigned short* o1pk = (unsigned short*)bump((size_t)Mpad * 2048 * 2);  // hi+lo
  unsigned short* w2pk = (unsigned short*)bump((size_t)32 * 8 * 512 * 2);
  float* as2           = (float*)bump((size_t)Mpad * 4);
  float* ad2           = (float*)bump((size_t)Mpad * 4);
  // aliases (safe: single-stream ordering; last reader precedes first writer)
  float* h2p = (float*)h1b;   // 4*Mpad*64*4B = Mpad*1KB <= Mpad*2KB
  float* h2  = (float*)xpk;   // Mpad*64*4B = Mpad*256B <= Mpad*1KB

  // CSR + packing
  hipMemsetAsync(counts, 0, (size_t)N * 4, stream);
  {
    int gridsz = (E + 255) / 256 + MB1 * 8 + 64 + 32;
    prep_fused<<<gridsz, 256, 0, stream>>>(ei, counts, E, x, xpk, N, MB1,
                                           W1, w1pk, W2, w2pk);
  }
  scan_blk<<<NB, 256, 0, stream>>>(counts, offsets, bsum, N);
  scan_apply<<<NB, 256, 0, stream>>>(offsets, cursors, bsum, NB, N);
  fill_all<<<(E + N + 255) / 256, 256, 0, stream>>>(ei, cursors, offsets, list, E, N);

  // layer 1
  gemm1_att<<<dim3(MB1, 8), 256, 49152, stream>>>(xpk, w1pk, asrc1, adst1, h1b, as1, ad1);
  agg1_gather8<<<(N + 7) / 8, 512, 0, stream>>>(h1b, as1, ad1, offsets, list, b1, o1pk, N);

  // layer 2
  gemm2_splitk<<<dim3(MB1, 4), 256, 32768, stream>>>(o1pk, w2pk, h2p, Mpad);
  reduce_att2<<<(N + 3) / 4, 256, 0, stream>>>(h2p, asrc2, adst2, h2, as2, ad2, Mpad, N);
  agg2_gather<<<(N + 3) / 4, 256, 0, stream>>>(h2, as2, ad2, offsets, list, b2, out, N);
}

// Round 7
// 162.265 us; speedup vs baseline: 1.2511x; 1.0138x over previous
//
#include <hip/hip_runtime.h>
#include <cmath>

// ---------------------------------------------------------------------------
// 2-layer GAT, N=10000, E=160000(+self loops in CSR), F_IN=256 ->
// [8x128 concat]=1024 -> ELU -> [1x64]. Split-bf16 MFMA GEMMs (3-term),
// tile-linear packed operands. gemm1: 128x128 tile, 512thr, dbuf 64KB.
// agg1: software-pipelined one-wave-per-node gather, LDS-staged packed out.
// ---------------------------------------------------------------------------

typedef short bf16x8 __attribute__((ext_vector_type(8)));
typedef float f32x4 __attribute__((ext_vector_type(4)));
typedef unsigned short u16x8 __attribute__((ext_vector_type(8)));

__device__ __forceinline__ float lrelu(float x) { return x > 0.f ? x : 0.2f * x; }
__device__ __forceinline__ float b2f(unsigned short h) {
  return __uint_as_float(((unsigned)h) << 16);
}
__device__ __forceinline__ unsigned short f2bf(float f) {
  unsigned u = __float_as_uint(f);
  u += 0x7FFFu + ((u >> 16) & 1u);
  return (unsigned short)(u >> 16);
}

__device__ __forceinline__ void fma8(float* acc, uint4 v, float e) {
  acc[0] += e * __uint_as_float(v.x << 16);
  acc[1] += e * __uint_as_float(v.x & 0xffff0000u);
  acc[2] += e * __uint_as_float(v.y << 16);
  acc[3] += e * __uint_as_float(v.y & 0xffff0000u);
  acc[4] += e * __uint_as_float(v.z << 16);
  acc[5] += e * __uint_as_float(v.z & 0xffff0000u);
  acc[6] += e * __uint_as_float(v.w << 16);
  acc[7] += e * __uint_as_float(v.w & 0xffff0000u);
}

#define GLOAD_LDS16(gsrc, ldst)                                              \
  __builtin_amdgcn_global_load_lds(                                          \
      (const __attribute__((address_space(1))) unsigned int*)(gsrc),         \
      (__attribute__((address_space(3))) unsigned int*)(ldst), 16, 0, 0)

// ---- fused prep: count (atomics) + pack_x + pack_w1 + pack_w2 -------------

__global__ __launch_bounds__(256) void prep_fused(
    const int* __restrict__ ei, int* __restrict__ counts, int E,
    const float* __restrict__ x, unsigned short* __restrict__ xpk, int N, int MB1,
    const float* __restrict__ W1, unsigned short* __restrict__ w1pk,
    const float* __restrict__ W2, unsigned short* __restrict__ w2pk) {
  const int countB = (E + 255) / 256;
  const int pxB = MB1 * 8;
  int bid = blockIdx.x;
  int t = threadIdx.x;

  if (bid < countB) {  // ---- degree count
    int e = bid * 256 + t;
    if (e < E) atomicAdd(&counts[ei[E + e]], 1);
    return;
  }
  bid -= countB;
  if (bid < pxB) {  // ---- pack x (hi/lo split, zero-padded rows)
    int mb = bid >> 3, ks = bid & 7;
    int l = t & 63, f = t >> 6;
    int row = mb * 64 + f * 16 + (l & 15);
    int kc = ks * 32 + (l >> 4) * 8;
    float v[8];
#pragma unroll
    for (int j = 0; j < 8; ++j) v[j] = 0.f;
    if (row < N) {
      const float* xr = x + (size_t)row * 256 + kc;
#pragma unroll
      for (int j = 0; j < 8; ++j) v[j] = xr[j];
    }
    u16x8 hi, lo;
#pragma unroll
    for (int j = 0; j < 8; ++j) {
      unsigned short h = f2bf(v[j]);
      hi[j] = h; lo[j] = f2bf(v[j] - b2f(h));
    }
    size_t base = (size_t)(mb * 8 + ks) * 8 * 512;
    *(u16x8*)(xpk + base + (size_t)f * 512 + l * 8) = hi;
    *(u16x8*)(xpk + base + (size_t)(4 + f) * 512 + l * 8) = lo;
    return;
  }
  bid -= pxB;
  if (bid < 64) {  // ---- pack W1^T
    int hb = bid >> 3, ks = bid & 7;
    int l = t & 63, gq = t >> 6;
    for (int g = gq; g < 8; g += 4) {
      int n = hb * 128 + g * 16 + (l & 15);
      int k0 = ks * 32 + (l >> 4) * 8;
      u16x8 hi, lo;
#pragma unroll
      for (int j = 0; j < 8; ++j) {
        float v = W1[(size_t)(k0 + j) * 1024 + n];
        unsigned short h = f2bf(v);
        hi[j] = h; lo[j] = f2bf(v - b2f(h));
      }
      size_t base = (size_t)(hb * 8 + ks) * 16 * 512;
      *(u16x8*)(w1pk + base + (size_t)g * 512 + l * 8) = hi;
      *(u16x8*)(w1pk + base + (size_t)(8 + g) * 512 + l * 8) = lo;
    }
    return;
  }
  bid -= 64;
  {  // ---- pack W2^T (32 blocks)
    int ks = bid;
    int l = t & 63, g = t >> 6;
    int n = g * 16 + (l & 15);
    int k0 = ks * 32 + (l >> 4) * 8;
    u16x8 hi, lo;
#pragma unroll
    for (int j = 0; j < 8; ++j) {
      float v = W2[(size_t)(k0 + j) * 64 + n];
      unsigned short h = f2bf(v);
      hi[j] = h; lo[j] = f2bf(v - b2f(h));
    }
    size_t base = (size_t)ks * 8 * 512;
    *(u16x8*)(w2pk + base + (size_t)g * 512 + l * 8) = hi;
    *(u16x8*)(w2pk + base + (size_t)(4 + g) * 512 + l * 8) = lo;
  }
}

// ---- CSR scan (v[i] = counts[i] + 1 for self loop) ------------------------

__global__ __launch_bounds__(256) void scan_blk(const int* __restrict__ counts,
                                                int* __restrict__ offsets,
                                                int* __restrict__ bsum, int n) {
  __shared__ int lds[256];
  int b = blockIdx.x, t = threadIdx.x, i = b * 256 + t;
  int v = (i < n) ? counts[i] + 1 : 0;
  lds[t] = v;
  __syncthreads();
  for (int off = 1; off < 256; off <<= 1) {
    int tv = (t >= off) ? lds[t - off] : 0;
    __syncthreads();
    lds[t] += tv;
    __syncthreads();
  }
  if (i < n) offsets[i] = lds[t] - v;
  if (t == 255) bsum[b] = lds[255];
}

__global__ __launch_bounds__(256) void scan_apply(int* __restrict__ offsets,
                                                  int* __restrict__ cursors,
                                                  const int* __restrict__ bsum,
                                                  int nb, int n) {
  __shared__ int pre_s;
  int b = blockIdx.x, t = threadIdx.x;
  if (t == 0) {
    int s = 0;
    for (int i = 0; i < b; ++i) s += bsum[i];
    pre_s = s;
    if (b == nb - 1) {
      int tot = s;
      for (int i = b; i < nb; ++i) tot += bsum[i];
      offsets[n] = tot;
    }
  }
  __syncthreads();
  int i = b * 256 + t;
  if (i < n) {
    int o = offsets[i] + pre_s;
    offsets[i] = o;
    cursors[i] = o;
  }
}

__global__ __launch_bounds__(256) void fill_all(const int* __restrict__ ei,
                                                int* __restrict__ cursors,
                                                const int* __restrict__ offsets,
                                                int* __restrict__ list,
                                                int E, int n) {
  int tid = blockIdx.x * 256 + threadIdx.x;
  if (tid < E) {
    int d = ei[E + tid];
    int pos = atomicAdd(&cursors[d], 1);
    list[pos] = ei[tid];
  } else if (tid < E + n) {
    int i = tid - E;
    list[offsets[i + 1] - 1] = i;  // self loop in last slot
  }
}

// ---- GEMM1 (split-bf16 MFMA) + fused att1 dots ----------------------------
// BM=128, BN=128 (one head), BK=32, 512 thr (8 waves: 2 row x 4 col).
// LDS per buf 32KB: [A-hi 8K][A-lo 8K][B-hi 8K][B-lo 8K]; dbuf = 64KB.

__global__ __launch_bounds__(512, 4) void gemm1_att(
    const unsigned short* __restrict__ xpk, const unsigned short* __restrict__ w1pk,
    const float* __restrict__ asrc, const float* __restrict__ adst,
    unsigned short* __restrict__ h1b, float* __restrict__ as1,
    float* __restrict__ ad1) {
  extern __shared__ char sm[];
  const int t = threadIdx.x, wid = t >> 6, lane = t & 63;
  const int wr = wid >> 2, wc = wid & 3;
  const int mb = blockIdx.x, hb = blockIdx.y;
  const int m0 = mb * 128;
  const int l15 = lane & 15, l4 = lane >> 4;

  f32x4 acc[4][2] = {};

  auto stage = [&](int buf, int ks) {
    char* base0 = sm + buf * 32768;
    for (int i = wid; i < 32; i += 8) {
      const unsigned short* src;
      int ldsoff;
      if (i < 8) {  // A-hi subtile f=i (rows f*16..f*16+15)
        int r = i >> 2;
        src = xpk + (size_t)((2 * mb + r) * 8 + ks) * 4096 + (i & 3) * 512 + lane * 8;
        ldsoff = i * 1024;
      } else if (i < 16) {  // A-lo
        int f = i - 8, r = f >> 2;
        src = xpk + (size_t)((2 * mb + r) * 8 + ks) * 4096 + (4 + (f & 3)) * 512 + lane * 8;
        ldsoff = 8192 + f * 1024;
      } else if (i < 24) {  // B-hi g=i-16
        int g = i - 16;
        src = w1pk + (size_t)(hb * 8 + ks) * 8192 + g * 512 + lane * 8;
        ldsoff = 16384 + g * 1024;
      } else {  // B-lo
        int g = i - 24;
        src = w1pk + (size_t)(hb * 8 + ks) * 8192 + (8 + g) * 512 + lane * 8;
        ldsoff = 24576 + g * 1024;
      }
      GLOAD_LDS16(src, base0 + ldsoff);
    }
  };

  stage(0, 0);
  __syncthreads();
  int buf = 0;
  for (int step = 0; step < 8; ++step) {
    if (step < 7) stage(buf ^ 1, step + 1);
    const char* b = sm + buf * 32768;
    bf16x8 ah[4], al[4], bh[2], bl[2];
#pragma unroll
    for (int mf = 0; mf < 4; ++mf) {
      ah[mf] = *(const bf16x8*)(b + (wr * 4 + mf) * 1024 + lane * 16);
      al[mf] = *(const bf16x8*)(b + 8192 + (wr * 4 + mf) * 1024 + lane * 16);
    }
#pragma unroll
    for (int nf = 0; nf < 2; ++nf) {
      bh[nf] = *(const bf16x8*)(b + 16384 + (wc * 2 + nf) * 1024 + lane * 16);
      bl[nf] = *(const bf16x8*)(b + 24576 + (wc * 2 + nf) * 1024 + lane * 16);
    }
#pragma unroll
    for (int mf = 0; mf < 4; ++mf)
#pragma unroll
      for (int nf = 0; nf < 2; ++nf) {
        acc[mf][nf] = __builtin_amdgcn_mfma_f32_16x16x32_bf16(ah[mf], bh[nf], acc[mf][nf], 0, 0, 0);
        acc[mf][nf] = __builtin_amdgcn_mfma_f32_16x16x32_bf16(ah[mf], bl[nf], acc[mf][nf], 0, 0, 0);
        acc[mf][nf] = __builtin_amdgcn_mfma_f32_16x16x32_bf16(al[mf], bh[nf], acc[mf][nf], 0, 0, 0);
      }
    __syncthreads();
    buf ^= 1;
  }

  // epilogue: fused att dots + bf16 C-tile via LDS (coalesced out)
  float* parts_s = (float*)sm;                           // [128][4]
  float* parts_d = (float*)(sm + 2048);                  // [128][4]
  unsigned short* ctile = (unsigned short*)(sm + 4096);  // [128][128]
  float as_c[2], ad_c[2];
#pragma unroll
  for (int nf = 0; nf < 2; ++nf) {
    int col = hb * 128 + wc * 32 + nf * 16 + l15;
    as_c[nf] = asrc[col];
    ad_c[nf] = adst[col];
  }
#pragma unroll
  for (int mf = 0; mf < 4; ++mf) {
    float ss[4] = {0.f, 0.f, 0.f, 0.f}, dd[4] = {0.f, 0.f, 0.f, 0.f};
#pragma unroll
    for (int nf = 0; nf < 2; ++nf)
#pragma unroll
      for (int r = 0; r < 4; ++r) {
        ss[r] += acc[mf][nf][r] * as_c[nf];
        dd[r] += acc[mf][nf][r] * ad_c[nf];
      }
#pragma unroll
    for (int r = 0; r < 4; ++r)
      for (int m = 1; m < 16; m <<= 1) {
        ss[r] += __shfl_xor(ss[r], m);
        dd[r] += __shfl_xor(dd[r], m);
      }
    if (l15 == 0) {
#pragma unroll
      for (int r = 0; r < 4; ++r) {
        int row = wr * 64 + mf * 16 + l4 * 4 + r;
        parts_s[row * 4 + wc] = ss[r];
        parts_d[row * 4 + wc] = dd[r];
      }
    }
#pragma unroll
    for (int nf = 0; nf < 2; ++nf)
#pragma unroll
      for (int r = 0; r < 4; ++r) {
        int row = wr * 64 + mf * 16 + l4 * 4 + r;
        int col = wc * 32 + nf * 16 + l15;
        ctile[row * 128 + col] = f2bf(acc[mf][nf][r]);
      }
  }
  __syncthreads();
  if (t < 128) {
    float s = parts_s[t * 4] + parts_s[t * 4 + 1] + parts_s[t * 4 + 2] + parts_s[t * 4 + 3];
    float d = parts_d[t * 4] + parts_d[t * 4 + 1] + parts_d[t * 4 + 2] + parts_d[t * 4 + 3];
    as1[(size_t)(m0 + t) * 8 + hb] = s;
    ad1[(size_t)(m0 + t) * 8 + hb] = d;
  }
#pragma unroll
  for (int rep = 0; rep < 4; ++rep) {
    int e = rep * 4096 + t * 8;
    int row = e >> 7, col = e & 127;
    bf16x8 v = *(const bf16x8*)(ctile + e);
    *(bf16x8*)(h1b + (size_t)(m0 + row) * 1024 + hb * 128 + col) = v;
  }
}

// ---- layer-1 gather: one wave per node, 2-deep software pipeline ----------
// Lane l owns channels [l*8,l*8+8) (head l>>4) and [512+l*8,...) (head 4+l>>4).
// 4 nodes per 256-thr block; packed o1pk image staged in 16KB LDS, written
// out as 64B-aligned runs.

__global__ __launch_bounds__(256) void agg1_gather(
    const unsigned short* __restrict__ h1b, const float* __restrict__ as1,
    const float* __restrict__ ad1, const int* __restrict__ offsets,
    const int* __restrict__ list, const float* __restrict__ b1,
    unsigned short* __restrict__ o1pk, int n) {
  __shared__ __align__(16) unsigned short stg[8192];  // 16 KB
  const int t = threadIdx.x, w = t >> 6, lane = t & 63;
  const int node = blockIdx.x * 4 + w;
  const int h0 = lane >> 4, h1_ = h0 + 4;

  if (node < n) {
    const int beg = offsets[node], end = offsets[node + 1];
    const float ad0 = ad1[(size_t)node * 8 + h0];
    const float ad4 = ad1[(size_t)node * 8 + h1_];
    float acc0[8] = {}, acc1[8] = {};
    float den0 = 0.f, den4 = 0.f;

    int j = beg;
    int sA = 0, sB = 0;
    float aA0 = 0.f, aA4 = 0.f, aB0 = 0.f, aB4 = 0.f;
    uint4 vA0, vA1, vB0, vB1;
    if (j + 2 <= end) {
      sA = list[j]; sB = list[j + 1];
      aA0 = as1[(size_t)sA * 8 + h0]; aA4 = as1[(size_t)sA * 8 + h1_];
      aB0 = as1[(size_t)sB * 8 + h0]; aB4 = as1[(size_t)sB * 8 + h1_];
      vA0 = *(const uint4*)(h1b + (size_t)sA * 1024 + lane * 8);
      vA1 = *(const uint4*)(h1b + (size_t)sA * 1024 + 512 + lane * 8);
      vB0 = *(const uint4*)(h1b + (size_t)sB * 1024 + lane * 8);
      vB1 = *(const uint4*)(h1b + (size_t)sB * 1024 + 512 + lane * 8);
    }
    for (; j + 4 <= end; j += 2) {
      // prefetch next pair (indices -> scalars -> rows), overlaps compute below
      int sA2 = list[j + 2], sB2 = list[j + 3];
      float aA02 = as1[(size_t)sA2 * 8 + h0], aA42 = as1[(size_t)sA2 * 8 + h1_];
      float aB02 = as1[(size_t)sB2 * 8 + h0], aB42 = as1[(size_t)sB2 * 8 + h1_];
      uint4 nA0 = *(const uint4*)(h1b + (size_t)sA2 * 1024 + lane * 8);
      uint4 nA1 = *(const uint4*)(h1b + (size_t)sA2 * 1024 + 512 + lane * 8);
      uint4 nB0 = *(const uint4*)(h1b + (size_t)sB2 * 1024 + lane * 8);
      uint4 nB1 = *(const uint4*)(h1b + (size_t)sB2 * 1024 + 512 + lane * 8);
      // compute resident pair
      float eA0 = __expf(lrelu(aA0 + ad0)), eA4 = __expf(lrelu(aA4 + ad4));
      float eB0 = __expf(lrelu(aB0 + ad0)), eB4 = __expf(lrelu(aB4 + ad4));
      den0 += eA0 + eB0; den4 += eA4 + eB4;
      fma8(acc0, vA0, eA0); fma8(acc1, vA1, eA4);
      fma8(acc0, vB0, eB0); fma8(acc1, vB1, eB4);
      // rotate
      sA = sA2; sB = sB2;
      aA0 = aA02; aA4 = aA42; aB0 = aB02; aB4 = aB42;
      vA0 = nA0; vA1 = nA1; vB0 = nB0; vB1 = nB1;
    }
    if (j + 2 <= end) {  // resident pair
      float eA0 = __expf(lrelu(aA0 + ad0)), eA4 = __expf(lrelu(aA4 + ad4));
      float eB0 = __expf(lrelu(aB0 + ad0)), eB4 = __expf(lrelu(aB4 + ad4));
      den0 += eA0 + eB0; den4 += eA4 + eB4;
      fma8(acc0, vA0, eA0); fma8(acc1, vA1, eA4);
      fma8(acc0, vB0, eB0); fma8(acc1, vB1, eB4);
      j += 2;
    }
    if (j < end) {  // single tail edge
      int s = list[j];
      float a0 = as1[(size_t)s * 8 + h0], a4 = as1[(size_t)s * 8 + h1_];
      uint4 v0 = *(const uint4*)(h1b + (size_t)s * 1024 + lane * 8);
      uint4 v1 = *(const uint4*)(h1b + (size_t)s * 1024 + 512 + lane * 8);
      float e0 = __expf(lrelu(a0 + ad0)), e4 = __expf(lrelu(a4 + ad4));
      den0 += e0; den4 += e4;
      fma8(acc0, v0, e0); fma8(acc1, v1, e4);
    }

    const float inv0 = 1.f / (den0 + 1e-16f);
    const float inv4 = 1.f / (den4 + 1e-16f);
    u16x8 hiA, loA, hiB, loB;
#pragma unroll
    for (int k = 0; k < 8; ++k) {
      float vA = acc0[k] * inv0 + b1[lane * 8 + k];
      float vB = acc1[k] * inv4 + b1[512 + lane * 8 + k];
      vA = vA > 0.f ? vA : expm1f(vA);
      vB = vB > 0.f ? vB : expm1f(vB);
      unsigned short hA = f2bf(vA), hB = f2bf(vB);
      hiA[k] = hA; loA[k] = f2bf(vA - b2f(hA));
      hiB[k] = hB; loB[k] = f2bf(vB - b2f(hB));
    }
    // stage: layout [ks 32][half 2][kc 4][w 4][16B], XOR-swizzled by (ks&7)<<4
    const int q2 = lane >> 2, kc = lane & 3;
    {
      int aw = q2 * 512 + kc * 64 + w * 16;
      *(u16x8*)((char*)stg + (aw ^ ((q2 & 7) << 4))) = hiA;
      aw += 256;
      *(u16x8*)((char*)stg + (aw ^ ((q2 & 7) << 4))) = loA;
    }
    {
      int ks = 16 + q2;
      int aw = ks * 512 + kc * 64 + w * 16;
      *(u16x8*)((char*)stg + (aw ^ ((ks & 7) << 4))) = hiB;
      aw += 256;
      *(u16x8*)((char*)stg + (aw ^ ((ks & 7) << 4))) = loB;
    }
  }
  __syncthreads();
  // coalesced copy-out: 4 iters x 256 thr x 16B = 16KB, 64B-aligned runs.
  const int blk = blockIdx.x;
  const int mb = blk >> 4, f = (blk >> 2) & 3, l15b = (blk & 3) * 4;
#pragma unroll
  for (int it = 0; it < 4; ++it) {
    int a = it * 4096 + t * 16;
    int ks = a >> 9, half = (a >> 8) & 1, kcc = (a >> 6) & 3, ww = (a >> 4) & 3;
    u16x8 v = *(const u16x8*)((const char*)stg + (a ^ ((ks & 7) << 4)));
    size_t g = (size_t)(mb * 32 + ks) * 4096 + half * 2048 + (size_t)f * 512 +
               (size_t)(kcc * 16 + l15b + ww) * 8;
    *(u16x8*)(o1pk + g) = v;
  }
}

// ---- GEMM2 (split-bf16 MFMA, split-K=4) -----------------------------------

__global__ __launch_bounds__(256) void gemm2_splitk(
    const unsigned short* __restrict__ o1pk, const unsigned short* __restrict__ w2pk,
    float* __restrict__ h2p, int Mpad) {
  extern __shared__ char sm[];
  const int t = threadIdx.x, wid = t >> 6, lane = t & 63;
  const int wr = wid >> 1, wc = wid & 1;
  const int mb = blockIdx.x, sk = blockIdx.y;
  const int m0 = mb * 64;
  const int l15 = lane & 15, l4 = lane >> 4;

  f32x4 acc[2][2] = {};

  auto stage = [&](int buf, int ks) {
    char* base0 = sm + buf * 16384;
    const unsigned short* ax = o1pk + (size_t)(mb * 32 + ks) * 8 * 512 + lane * 8;
    for (int i = wid; i < 8; i += 4)
      GLOAD_LDS16(ax + i * 512, base0 + i * 1024);
    const unsigned short* bw = w2pk + (size_t)ks * 8 * 512 + lane * 8;
    for (int i = wid; i < 8; i += 4)
      GLOAD_LDS16(bw + i * 512, base0 + 8192 + i * 1024);
  };

  stage(0, sk * 8);
  __syncthreads();
  int buf = 0;
  for (int step = 0; step < 8; ++step) {
    if (step < 7) stage(buf ^ 1, sk * 8 + step + 1);
    const char* b = sm + buf * 16384;
    bf16x8 ah[2], al[2], bh[2], bl[2];
#pragma unroll
    for (int mf = 0; mf < 2; ++mf) {
      int f = wr * 2 + mf;
      ah[mf] = *(const bf16x8*)(b + f * 1024 + lane * 16);
      al[mf] = *(const bf16x8*)(b + 4096 + f * 1024 + lane * 16);
    }
#pragma unroll
    for (int nf = 0; nf < 2; ++nf) {
      int g = wc * 2 + nf;
      bh[nf] = *(const bf16x8*)(b + 8192 + g * 1024 + lane * 16);
      bl[nf] = *(const bf16x8*)(b + 12288 + g * 1024 + lane * 16);
    }
#pragma unroll
    for (int mf = 0; mf < 2; ++mf)
#pragma unroll
      for (int nf = 0; nf < 2; ++nf) {
        acc[mf][nf] = __builtin_amdgcn_mfma_f32_16x16x32_bf16(ah[mf], bh[nf], acc[mf][nf], 0, 0, 0);
        acc[mf][nf] = __builtin_amdgcn_mfma_f32_16x16x32_bf16(ah[mf], bl[nf], acc[mf][nf], 0, 0, 0);
        acc[mf][nf] = __builtin_amdgcn_mfma_f32_16x16x32_bf16(al[mf], bh[nf], acc[mf][nf], 0, 0, 0);
      }
    __syncthreads();
    buf ^= 1;
  }

#pragma unroll
  for (int mf = 0; mf < 2; ++mf)
#pragma unroll
    for (int nf = 0; nf < 2; ++nf)
#pragma unroll
      for (int r = 0; r < 4; ++r) {
        int row = wr * 32 + mf * 16 + l4 * 4 + r;
        int col = wc * 32 + nf * 16 + l15;
        h2p[((size_t)sk * Mpad + m0 + row) * 64 + col] = acc[mf][nf][r];
      }
}

// ---- reduce split-K partials + att2 dots ----------------------------------

__global__ __launch_bounds__(256) void reduce_att2(
    const float* __restrict__ h2p, const float* __restrict__ asrc,
    const float* __restrict__ adst, float* __restrict__ h2,
    float* __restrict__ as2, float* __restrict__ ad2, int Mpad, int n) {
  int w = threadIdx.x >> 6, lane = threadIdx.x & 63;
  int row = blockIdx.x * 4 + w;
  if (row >= n) return;
  float s = 0.f;
#pragma unroll
  for (int sk = 0; sk < 4; ++sk) s += h2p[((size_t)sk * Mpad + row) * 64 + lane];
  h2[(size_t)row * 64 + lane] = s;
  float ds = s * asrc[lane], dd = s * adst[lane];
  for (int o = 32; o; o >>= 1) { ds += __shfl_xor(ds, o); dd += __shfl_xor(dd, o); }
  if (lane == 0) { as2[row] = ds; ad2[row] = dd; }
}

// ---- layer-2 gather: one wave per node, fused e+den -----------------------

__global__ __launch_bounds__(256) void agg2_gather(
    const float* __restrict__ h2, const float* __restrict__ as2,
    const float* __restrict__ ad2, const int* __restrict__ offsets,
    const int* __restrict__ list, const float* __restrict__ b2,
    float* __restrict__ out, int n) {
  const int wid = threadIdx.x >> 6, lane = threadIdx.x & 63;
  const int node = blockIdx.x * 4 + wid;
  if (node >= n) return;
  const int beg = offsets[node], end = offsets[node + 1];
  const float ad = ad2[node];
  const int cb = (lane & 15) * 4;  // 4 channels per lane
  const int jo = lane >> 4;        // row-in-quad

  float4 acc = make_float4(0.f, 0.f, 0.f, 0.f);
  float den = 0.f;
  for (int j = beg + jo; j < end; j += 4) {
    int s = list[j];
    float e = __expf(lrelu(as2[s] + ad));
    den += e;
    float4 v = *(const float4*)&h2[(size_t)s * 64 + cb];
    acc.x += e * v.x; acc.y += e * v.y; acc.z += e * v.z; acc.w += e * v.w;
  }
  acc.x += __shfl_xor(acc.x, 16); acc.y += __shfl_xor(acc.y, 16);
  acc.z += __shfl_xor(acc.z, 16); acc.w += __shfl_xor(acc.w, 16);
  den += __shfl_xor(den, 16);
  acc.x += __shfl_xor(acc.x, 32); acc.y += __shfl_xor(acc.y, 32);
  acc.z += __shfl_xor(acc.z, 32); acc.w += __shfl_xor(acc.w, 32);
  den += __shfl_xor(den, 32);
  if (jo == 0) {
    float inv = 1.f / (den + 1e-16f);
    float4 r;
    r.x = acc.x * inv + b2[cb];
    r.y = acc.y * inv + b2[cb + 1];
    r.z = acc.z * inv + b2[cb + 2];
    r.w = acc.w * inv + b2[cb + 3];
    *(float4*)&out[(size_t)node * 64 + cb] = r;
  }
}

// ---------------------------------------------------------------------------

extern "C" void kernel_launch(void* const* d_in, const int* in_sizes, int n_in,
                              void* d_out, int out_size, void* d_ws, size_t ws_size,
                              hipStream_t stream) {
  const float* x     = (const float*)d_in[0];
  const int*   ei    = (const int*)d_in[1];
  const float* W1    = (const float*)d_in[2];
  const float* asrc1 = (const float*)d_in[3];
  const float* adst1 = (const float*)d_in[4];
  const float* b1    = (const float*)d_in[5];
  const float* W2    = (const float*)d_in[6];
  const float* asrc2 = (const float*)d_in[7];
  const float* adst2 = (const float*)d_in[8];
  const float* b2    = (const float*)d_in[9];
  float* out = (float*)d_out;

  const int N = in_sizes[0] / 256;
  const int E = in_sizes[1] / 2;
  const int T = E + N;  // edges + self loops
  const int MBB = (N + 127) / 128;  // gemm1 M-blocks
  const int Mpad = MBB * 128;
  const int MB1 = Mpad / 64;        // 64-row pack blocks
  const int NB = (N + 255) / 256;

  char* p = (char*)d_ws;
  auto bump = [&](size_t bytes) {
    char* r = p;
    p += (bytes + 255) & ~(size_t)255;
    return r;
  };
  int* counts  = (int*)bump((size_t)N * 4);
  int* offsets = (int*)bump((size_t)(N + 1) * 4);
  int* cursors = (int*)bump((size_t)N * 4);
  int* bsum    = (int*)bump((size_t)NB * 4);
  int* list    = (int*)bump((size_t)T * 4);
  unsigned short* xpk  = (unsigned short*)bump((size_t)Mpad * 512 * 2);   // hi+lo
  unsigned short* w1pk = (unsigned short*)bump((size_t)8 * 8 * 16 * 512 * 2);
  unsigned short* h1b  = (unsigned short*)bump((size_t)Mpad * 1024 * 2);
  float* as1           = (float*)bump((size_t)Mpad * 8 * 4);
  float* ad1           = (float*)bump((size_t)Mpad * 8 * 4);
  unsigned short* o1pk = (unsigned short*)bump((size_t)Mpad * 2048 * 2);  // hi+lo
  unsigned short* w2pk = (unsigned short*)bump((size_t)32 * 8 * 512 * 2);
  float* as2           = (float*)bump((size_t)Mpad * 4);
  float* ad2           = (float*)bump((size_t)Mpad * 4);
  // aliases (safe: single-stream ordering; last reader precedes first writer)
  float* h2p = (float*)h1b;   // 4*Mpad*64*4B = Mpad*1KB <= Mpad*2KB
  float* h2  = (float*)xpk;   // Mpad*64*4B = Mpad*256B <= Mpad*1KB

  // CSR + packing
  hipMemsetAsync(counts, 0, (size_t)N * 4, stream);
  {
    int gridsz = (E + 255) / 256 + MB1 * 8 + 64 + 32;
    prep_fused<<<gridsz, 256, 0, stream>>>(ei, counts, E, x, xpk, N, MB1,
                                           W1, w1pk, W2, w2pk);
  }
  scan_blk<<<NB, 256, 0, stream>>>(counts, offsets, bsum, N);
  scan_apply<<<NB, 256, 0, stream>>>(offsets, cursors, bsum, NB, N);
  fill_all<<<(E + N + 255) / 256, 256, 0, stream>>>(ei, cursors, offsets, list, E, N);

  // layer 1
  gemm1_att<<<dim3(MBB, 8), 512, 65536, stream>>>(xpk, w1pk, asrc1, adst1, h1b, as1, ad1);
  agg1_gather<<<(N + 3) / 4, 256, 0, stream>>>(h1b, as1, ad1, offsets, list, b1, o1pk, N);

  // layer 2
  gemm2_splitk<<<dim3(Mpad / 64, 4), 256, 32768, stream>>>(o1pk, w2pk, h2p, Mpad);
  reduce_att2<<<(N + 3) / 4, 256, 0, stream>>>(h2p, asrc2, adst2, h2, as2, ad2, Mpad, N);
  agg2_gather<<<(N + 3) / 4, 256, 0, stream>>>(h2, as2, ad2, offsets, list, b2, out, N);
}

// Round 8
// 161.219 us; speedup vs baseline: 1.2592x; 1.0065x over previous
//
#include <hip/hip_runtime.h>
#include <cmath>

// ---------------------------------------------------------------------------
// 2-layer GAT, N=10000, E=160000(+self loops in CSR), F_IN=256 ->
// [8x128 concat]=1024 -> ELU -> [1x64]. GEMM1: 2-term split-bf16 MFMA
// (Ah*Bh + Ah*Bl), 128x128 tile. GEMM2: 3-term split-K. agg1: 4-wide 3-stage
// software-pipelined wave-per-node gather, LDS-staged packed out.
// ---------------------------------------------------------------------------

typedef short bf16x8 __attribute__((ext_vector_type(8)));
typedef float f32x4 __attribute__((ext_vector_type(4)));
typedef unsigned short u16x8 __attribute__((ext_vector_type(8)));

__device__ __forceinline__ float lrelu(float x) { return x > 0.f ? x : 0.2f * x; }
__device__ __forceinline__ float b2f(unsigned short h) {
  return __uint_as_float(((unsigned)h) << 16);
}
__device__ __forceinline__ unsigned short f2bf(float f) {
  unsigned u = __float_as_uint(f);
  u += 0x7FFFu + ((u >> 16) & 1u);
  return (unsigned short)(u >> 16);
}

__device__ __forceinline__ void fma8(float* acc, uint4 v, float e) {
  acc[0] += e * __uint_as_float(v.x << 16);
  acc[1] += e * __uint_as_float(v.x & 0xffff0000u);
  acc[2] += e * __uint_as_float(v.y << 16);
  acc[3] += e * __uint_as_float(v.y & 0xffff0000u);
  acc[4] += e * __uint_as_float(v.z << 16);
  acc[5] += e * __uint_as_float(v.z & 0xffff0000u);
  acc[6] += e * __uint_as_float(v.w << 16);
  acc[7] += e * __uint_as_float(v.w & 0xffff0000u);
}

#define GLOAD_LDS16(gsrc, ldst)                                              \
  __builtin_amdgcn_global_load_lds(                                          \
      (const __attribute__((address_space(1))) unsigned int*)(gsrc),         \
      (__attribute__((address_space(3))) unsigned int*)(ldst), 16, 0, 0)

// ---- fused prep: count (atomics) + pack_x(hi) + pack_w1(hi/lo) + pack_w2 --

__global__ __launch_bounds__(256) void prep_fused(
    const int* __restrict__ ei, int* __restrict__ counts, int E,
    const float* __restrict__ x, unsigned short* __restrict__ xpk, int N, int MB1,
    const float* __restrict__ W1, unsigned short* __restrict__ w1pk,
    const float* __restrict__ W2, unsigned short* __restrict__ w2pk) {
  const int countB = (E + 255) / 256;
  const int pxB = MB1 * 8;
  int bid = blockIdx.x;
  int t = threadIdx.x;

  if (bid < countB) {  // ---- degree count
    int e = bid * 256 + t;
    if (e < E) atomicAdd(&counts[ei[E + e]], 1);
    return;
  }
  bid -= countB;
  if (bid < pxB) {  // ---- pack x (hi only, zero-padded rows)
    int mb = bid >> 3, ks = bid & 7;
    int l = t & 63, f = t >> 6;
    int row = mb * 64 + f * 16 + (l & 15);
    int kc = ks * 32 + (l >> 4) * 8;
    float v[8];
#pragma unroll
    for (int j = 0; j < 8; ++j) v[j] = 0.f;
    if (row < N) {
      const float* xr = x + (size_t)row * 256 + kc;
#pragma unroll
      for (int j = 0; j < 8; ++j) v[j] = xr[j];
    }
    u16x8 hi;
#pragma unroll
    for (int j = 0; j < 8; ++j) hi[j] = f2bf(v[j]);
    size_t base = (size_t)(mb * 8 + ks) * 4 * 512;
    *(u16x8*)(xpk + base + (size_t)f * 512 + l * 8) = hi;
    return;
  }
  bid -= pxB;
  if (bid < 64) {  // ---- pack W1^T (hi + lo)
    int hb = bid >> 3, ks = bid & 7;
    int l = t & 63, gq = t >> 6;
    for (int g = gq; g < 8; g += 4) {
      int n = hb * 128 + g * 16 + (l & 15);
      int k0 = ks * 32 + (l >> 4) * 8;
      u16x8 hi, lo;
#pragma unroll
      for (int j = 0; j < 8; ++j) {
        float v = W1[(size_t)(k0 + j) * 1024 + n];
        unsigned short h = f2bf(v);
        hi[j] = h; lo[j] = f2bf(v - b2f(h));
      }
      size_t base = (size_t)(hb * 8 + ks) * 16 * 512;
      *(u16x8*)(w1pk + base + (size_t)g * 512 + l * 8) = hi;
      *(u16x8*)(w1pk + base + (size_t)(8 + g) * 512 + l * 8) = lo;
    }
    return;
  }
  bid -= 64;
  {  // ---- pack W2^T (hi + lo, 32 blocks)
    int ks = bid;
    int l = t & 63, g = t >> 6;
    int n = g * 16 + (l & 15);
    int k0 = ks * 32 + (l >> 4) * 8;
    u16x8 hi, lo;
#pragma unroll
    for (int j = 0; j < 8; ++j) {
      float v = W2[(size_t)(k0 + j) * 64 + n];
      unsigned short h = f2bf(v);
      hi[j] = h; lo[j] = f2bf(v - b2f(h));
    }
    size_t base = (size_t)ks * 8 * 512;
    *(u16x8*)(w2pk + base + (size_t)g * 512 + l * 8) = hi;
    *(u16x8*)(w2pk + base + (size_t)(4 + g) * 512 + l * 8) = lo;
  }
}

// ---- CSR scan (v[i] = counts[i] + 1 for self loop) ------------------------

__global__ __launch_bounds__(256) void scan_blk(const int* __restrict__ counts,
                                                int* __restrict__ offsets,
                                                int* __restrict__ bsum, int n) {
  __shared__ int lds[256];
  int b = blockIdx.x, t = threadIdx.x, i = b * 256 + t;
  int v = (i < n) ? counts[i] + 1 : 0;
  lds[t] = v;
  __syncthreads();
  for (int off = 1; off < 256; off <<= 1) {
    int tv = (t >= off) ? lds[t - off] : 0;
    __syncthreads();
    lds[t] += tv;
    __syncthreads();
  }
  if (i < n) offsets[i] = lds[t] - v;
  if (t == 255) bsum[b] = lds[255];
}

__global__ __launch_bounds__(256) void scan_apply(int* __restrict__ offsets,
                                                  int* __restrict__ cursors,
                                                  const int* __restrict__ bsum,
                                                  int nb, int n) {
  __shared__ int pre_s;
  int b = blockIdx.x, t = threadIdx.x;
  if (t == 0) {
    int s = 0;
    for (int i = 0; i < b; ++i) s += bsum[i];
    pre_s = s;
    if (b == nb - 1) {
      int tot = s;
      for (int i = b; i < nb; ++i) tot += bsum[i];
      offsets[n] = tot;
    }
  }
  __syncthreads();
  int i = b * 256 + t;
  if (i < n) {
    int o = offsets[i] + pre_s;
    offsets[i] = o;
    cursors[i] = o;
  }
}

__global__ __launch_bounds__(256) void fill_all(const int* __restrict__ ei,
                                                int* __restrict__ cursors,
                                                const int* __restrict__ offsets,
                                                int* __restrict__ list,
                                                int E, int n) {
  int tid = blockIdx.x * 256 + threadIdx.x;
  if (tid < E) {
    int d = ei[E + tid];
    int pos = atomicAdd(&cursors[d], 1);
    list[pos] = ei[tid];
  } else if (tid < E + n) {
    int i = tid - E;
    list[offsets[i + 1] - 1] = i;  // self loop in last slot
  }
}

// ---- GEMM1 (2-term split-bf16 MFMA) + fused att1 dots ---------------------
// BM=128, BN=128 (one head), BK=32, 512 thr (8 waves: 2 row x 4 col).
// LDS per buf 24KB: [A-hi 8K][B-hi 8K][B-lo 8K]; dbuf = 48KB.

__global__ __launch_bounds__(512, 4) void gemm1_att(
    const unsigned short* __restrict__ xpk, const unsigned short* __restrict__ w1pk,
    const float* __restrict__ asrc, const float* __restrict__ adst,
    unsigned short* __restrict__ h1b, float* __restrict__ as1,
    float* __restrict__ ad1) {
  extern __shared__ char sm[];
  const int t = threadIdx.x, wid = t >> 6, lane = t & 63;
  const int wr = wid >> 2, wc = wid & 3;
  const int mb = blockIdx.x, hb = blockIdx.y;
  const int m0 = mb * 128;
  const int l15 = lane & 15, l4 = lane >> 4;

  f32x4 acc[4][2] = {};

  auto stage = [&](int buf, int ks) {
    char* base0 = sm + buf * 24576;
    for (int i = wid; i < 24; i += 8) {
      const unsigned short* src;
      int ldsoff;
      if (i < 8) {  // A-hi subtile: pack-block r=i>>2, f=i&3
        int r = i >> 2;
        src = xpk + (size_t)((2 * mb + r) * 8 + ks) * 2048 + (i & 3) * 512 + lane * 8;
        ldsoff = i * 1024;
      } else if (i < 16) {  // B-hi g=i-8
        int g = i - 8;
        src = w1pk + (size_t)(hb * 8 + ks) * 8192 + g * 512 + lane * 8;
        ldsoff = 8192 + g * 1024;
      } else {  // B-lo g=i-16
        int g = i - 16;
        src = w1pk + (size_t)(hb * 8 + ks) * 8192 + (8 + g) * 512 + lane * 8;
        ldsoff = 16384 + g * 1024;
      }
      GLOAD_LDS16(src, base0 + ldsoff);
    }
  };

  stage(0, 0);
  __syncthreads();
  int buf = 0;
  for (int step = 0; step < 8; ++step) {
    if (step < 7) stage(buf ^ 1, step + 1);
    const char* b = sm + buf * 24576;
    bf16x8 ah[4], bh[2], bl[2];
#pragma unroll
    for (int mf = 0; mf < 4; ++mf)
      ah[mf] = *(const bf16x8*)(b + (wr * 4 + mf) * 1024 + lane * 16);
#pragma unroll
    for (int nf = 0; nf < 2; ++nf) {
      bh[nf] = *(const bf16x8*)(b + 8192 + (wc * 2 + nf) * 1024 + lane * 16);
      bl[nf] = *(const bf16x8*)(b + 16384 + (wc * 2 + nf) * 1024 + lane * 16);
    }
#pragma unroll
    for (int mf = 0; mf < 4; ++mf)
#pragma unroll
      for (int nf = 0; nf < 2; ++nf) {
        acc[mf][nf] = __builtin_amdgcn_mfma_f32_16x16x32_bf16(ah[mf], bh[nf], acc[mf][nf], 0, 0, 0);
        acc[mf][nf] = __builtin_amdgcn_mfma_f32_16x16x32_bf16(ah[mf], bl[nf], acc[mf][nf], 0, 0, 0);
      }
    __syncthreads();
    buf ^= 1;
  }

  // epilogue: fused att dots + bf16 C-tile via LDS (coalesced out)
  float* parts_s = (float*)sm;                           // [128][4]
  float* parts_d = (float*)(sm + 2048);                  // [128][4]
  unsigned short* ctile = (unsigned short*)(sm + 4096);  // [128][128]
  float as_c[2], ad_c[2];
#pragma unroll
  for (int nf = 0; nf < 2; ++nf) {
    int col = hb * 128 + wc * 32 + nf * 16 + l15;
    as_c[nf] = asrc[col];
    ad_c[nf] = adst[col];
  }
#pragma unroll
  for (int mf = 0; mf < 4; ++mf) {
    float ss[4] = {0.f, 0.f, 0.f, 0.f}, dd[4] = {0.f, 0.f, 0.f, 0.f};
#pragma unroll
    for (int nf = 0; nf < 2; ++nf)
#pragma unroll
      for (int r = 0; r < 4; ++r) {
        ss[r] += acc[mf][nf][r] * as_c[nf];
        dd[r] += acc[mf][nf][r] * ad_c[nf];
      }
#pragma unroll
    for (int r = 0; r < 4; ++r)
      for (int m = 1; m < 16; m <<= 1) {
        ss[r] += __shfl_xor(ss[r], m);
        dd[r] += __shfl_xor(dd[r], m);
      }
    if (l15 == 0) {
#pragma unroll
      for (int r = 0; r < 4; ++r) {
        int row = wr * 64 + mf * 16 + l4 * 4 + r;
        parts_s[row * 4 + wc] = ss[r];
        parts_d[row * 4 + wc] = dd[r];
      }
    }
#pragma unroll
    for (int nf = 0; nf < 2; ++nf)
#pragma unroll
      for (int r = 0; r < 4; ++r) {
        int row = wr * 64 + mf * 16 + l4 * 4 + r;
        int col = wc * 32 + nf * 16 + l15;
        ctile[row * 128 + col] = f2bf(acc[mf][nf][r]);
      }
  }
  __syncthreads();
  if (t < 128) {
    float s = parts_s[t * 4] + parts_s[t * 4 + 1] + parts_s[t * 4 + 2] + parts_s[t * 4 + 3];
    float d = parts_d[t * 4] + parts_d[t * 4 + 1] + parts_d[t * 4 + 2] + parts_d[t * 4 + 3];
    as1[(size_t)(m0 + t) * 8 + hb] = s;
    ad1[(size_t)(m0 + t) * 8 + hb] = d;
  }
#pragma unroll
  for (int rep = 0; rep < 4; ++rep) {
    int e = rep * 4096 + t * 8;
    int row = e >> 7, col = e & 127;
    bf16x8 v = *(const bf16x8*)(ctile + e);
    *(bf16x8*)(h1b + (size_t)(m0 + row) * 1024 + hb * 128 + col) = v;
  }
}

// ---- layer-1 gather: wave per node, 4-wide 3-stage pipeline ---------------
// Lane l owns channels [l*8,l*8+8) (head l>>4) and [512+l*8,...) (head 4+l>>4).
// Index queue 2 groups ahead; att+row data 1 group ahead.

__global__ __launch_bounds__(256) void agg1_gather(
    const unsigned short* __restrict__ h1b, const float* __restrict__ as1,
    const float* __restrict__ ad1, const int* __restrict__ offsets,
    const int* __restrict__ list, const float* __restrict__ b1,
    unsigned short* __restrict__ o1pk, int n) {
  __shared__ __align__(16) unsigned short stg[8192];  // 16 KB
  const int t = threadIdx.x, w = t >> 6, lane = t & 63;
  const int node = blockIdx.x * 4 + w;
  const int h0 = lane >> 4, h1_ = h0 + 4;

  if (node < n) {
    const int beg = offsets[node], end = offsets[node + 1];
    const float ad0 = ad1[(size_t)node * 8 + h0];
    const float ad4 = ad1[(size_t)node * 8 + h1_];
    float acc0[8] = {}, acc1[8] = {};
    float den0 = 0.f, den4 = 0.f;

    const int m = end - beg;
    const int* lp = list + beg;
    const int ng = m >> 2;

    int sCur[4], sNxt[4];
    float a0C[4], a4C[4];
    uint4 r0C[4], r1C[4];

    auto issue = [&](const int* s, float* a0, float* a4, uint4* r0, uint4* r1) {
#pragma unroll
      for (int k = 0; k < 4; ++k) {
        a0[k] = as1[(size_t)s[k] * 8 + h0];
        a4[k] = as1[(size_t)s[k] * 8 + h1_];
        r0[k] = *(const uint4*)(h1b + (size_t)s[k] * 1024 + lane * 8);
        r1[k] = *(const uint4*)(h1b + (size_t)s[k] * 1024 + 512 + lane * 8);
      }
    };
    auto compute = [&](const float* a0, const float* a4, const uint4* r0,
                       const uint4* r1) {
#pragma unroll
      for (int k = 0; k < 4; ++k) {
        float e0 = __expf(lrelu(a0[k] + ad0));
        float e4 = __expf(lrelu(a4[k] + ad4));
        den0 += e0; den4 += e4;
        fma8(acc0, r0[k], e0);
        fma8(acc1, r1[k], e4);
      }
    };

    if (ng >= 1) {
#pragma unroll
      for (int k = 0; k < 4; ++k) sCur[k] = lp[k];
      issue(sCur, a0C, a4C, r0C, r1C);
    }
    if (ng >= 2) {
#pragma unroll
      for (int k = 0; k < 4; ++k) sNxt[k] = lp[4 + k];
    }
#pragma unroll 2
    for (int g = 0; g < ng; ++g) {
      int sNew[4] = {0, 0, 0, 0};
      if (g + 2 < ng) {
#pragma unroll
        for (int k = 0; k < 4; ++k) sNew[k] = lp[(g + 2) * 4 + k];
      }
      float a0N[4], a4N[4];
      uint4 r0N[4], r1N[4];
      if (g + 1 < ng) issue(sNxt, a0N, a4N, r0N, r1N);
      compute(a0C, a4C, r0C, r1C);
#pragma unroll
      for (int k = 0; k < 4; ++k) {
        sCur[k] = sNxt[k]; sNxt[k] = sNew[k];
        a0C[k] = a0N[k]; a4C[k] = a4N[k];
        r0C[k] = r0N[k]; r1C[k] = r1N[k];
      }
    }
    for (int j = ng * 4; j < m; ++j) {  // tail (<4 edges)
      int s = lp[j];
      float a0 = as1[(size_t)s * 8 + h0], a4 = as1[(size_t)s * 8 + h1_];
      uint4 v0 = *(const uint4*)(h1b + (size_t)s * 1024 + lane * 8);
      uint4 v1 = *(const uint4*)(h1b + (size_t)s * 1024 + 512 + lane * 8);
      float e0 = __expf(lrelu(a0 + ad0)), e4 = __expf(lrelu(a4 + ad4));
      den0 += e0; den4 += e4;
      fma8(acc0, v0, e0); fma8(acc1, v1, e4);
    }

    const float inv0 = 1.f / (den0 + 1e-16f);
    const float inv4 = 1.f / (den4 + 1e-16f);
    u16x8 hiA, loA, hiB, loB;
#pragma unroll
    for (int k = 0; k < 8; ++k) {
      float vA = acc0[k] * inv0 + b1[lane * 8 + k];
      float vB = acc1[k] * inv4 + b1[512 + lane * 8 + k];
      vA = vA > 0.f ? vA : expm1f(vA);
      vB = vB > 0.f ? vB : expm1f(vB);
      unsigned short hA = f2bf(vA), hB = f2bf(vB);
      hiA[k] = hA; loA[k] = f2bf(vA - b2f(hA));
      hiB[k] = hB; loB[k] = f2bf(vB - b2f(hB));
    }
    // stage: layout [ks 32][half 2][kc 4][w 4][16B], XOR-swizzled by (ks&7)<<4
    const int q2 = lane >> 2, kc = lane & 3;
    {
      int aw = q2 * 512 + kc * 64 + w * 16;
      *(u16x8*)((char*)stg + (aw ^ ((q2 & 7) << 4))) = hiA;
      aw += 256;
      *(u16x8*)((char*)stg + (aw ^ ((q2 & 7) << 4))) = loA;
    }
    {
      int ks = 16 + q2;
      int aw = ks * 512 + kc * 64 + w * 16;
      *(u16x8*)((char*)stg + (aw ^ ((ks & 7) << 4))) = hiB;
      aw += 256;
      *(u16x8*)((char*)stg + (aw ^ ((ks & 7) << 4))) = loB;
    }
  }
  __syncthreads();
  // coalesced copy-out: 4 iters x 256 thr x 16B = 16KB, 64B-aligned runs.
  const int blk = blockIdx.x;
  const int mb = blk >> 4, f = (blk >> 2) & 3, l15b = (blk & 3) * 4;
#pragma unroll
  for (int it = 0; it < 4; ++it) {
    int a = it * 4096 + t * 16;
    int ks = a >> 9, half = (a >> 8) & 1, kcc = (a >> 6) & 3, ww = (a >> 4) & 3;
    u16x8 v = *(const u16x8*)((const char*)stg + (a ^ ((ks & 7) << 4)));
    size_t g = (size_t)(mb * 32 + ks) * 4096 + half * 2048 + (size_t)f * 512 +
               (size_t)(kcc * 16 + l15b + ww) * 8;
    *(u16x8*)(o1pk + g) = v;
  }
}

// ---- GEMM2 (split-bf16 MFMA, split-K=4) -----------------------------------

__global__ __launch_bounds__(256) void gemm2_splitk(
    const unsigned short* __restrict__ o1pk, const unsigned short* __restrict__ w2pk,
    float* __restrict__ h2p, int Mpad) {
  extern __shared__ char sm[];
  const int t = threadIdx.x, wid = t >> 6, lane = t & 63;
  const int wr = wid >> 1, wc = wid & 1;
  const int mb = blockIdx.x, sk = blockIdx.y;
  const int m0 = mb * 64;
  const int l15 = lane & 15, l4 = lane >> 4;

  f32x4 acc[2][2] = {};

  auto stage = [&](int buf, int ks) {
    char* base0 = sm + buf * 16384;
    const unsigned short* ax = o1pk + (size_t)(mb * 32 + ks) * 8 * 512 + lane * 8;
    for (int i = wid; i < 8; i += 4)
      GLOAD_LDS16(ax + i * 512, base0 + i * 1024);
    const unsigned short* bw = w2pk + (size_t)ks * 8 * 512 + lane * 8;
    for (int i = wid; i < 8; i += 4)
      GLOAD_LDS16(bw + i * 512, base0 + 8192 + i * 1024);
  };

  stage(0, sk * 8);
  __syncthreads();
  int buf = 0;
  for (int step = 0; step < 8; ++step) {
    if (step < 7) stage(buf ^ 1, sk * 8 + step + 1);
    const char* b = sm + buf * 16384;
    bf16x8 ah[2], al[2], bh[2], bl[2];
#pragma unroll
    for (int mf = 0; mf < 2; ++mf) {
      int f = wr * 2 + mf;
      ah[mf] = *(const bf16x8*)(b + f * 1024 + lane * 16);
      al[mf] = *(const bf16x8*)(b + 4096 + f * 1024 + lane * 16);
    }
#pragma unroll
    for (int nf = 0; nf < 2; ++nf) {
      int g = wc * 2 + nf;
      bh[nf] = *(const bf16x8*)(b + 8192 + g * 1024 + lane * 16);
      bl[nf] = *(const bf16x8*)(b + 12288 + g * 1024 + lane * 16);
    }
#pragma unroll
    for (int mf = 0; mf < 2; ++mf)
#pragma unroll
      for (int nf = 0; nf < 2; ++nf) {
        acc[mf][nf] = __builtin_amdgcn_mfma_f32_16x16x32_bf16(ah[mf], bh[nf], acc[mf][nf], 0, 0, 0);
        acc[mf][nf] = __builtin_amdgcn_mfma_f32_16x16x32_bf16(ah[mf], bl[nf], acc[mf][nf], 0, 0, 0);
        acc[mf][nf] = __builtin_amdgcn_mfma_f32_16x16x32_bf16(al[mf], bh[nf], acc[mf][nf], 0, 0, 0);
      }
    __syncthreads();
    buf ^= 1;
  }

#pragma unroll
  for (int mf = 0; mf < 2; ++mf)
#pragma unroll
    for (int nf = 0; nf < 2; ++nf)
#pragma unroll
      for (int r = 0; r < 4; ++r) {
        int row = wr * 32 + mf * 16 + l4 * 4 + r;
        int col = wc * 32 + nf * 16 + l15;
        h2p[((size_t)sk * Mpad + m0 + row) * 64 + col] = acc[mf][nf][r];
      }
}

// ---- reduce split-K partials + att2 dots ----------------------------------

__global__ __launch_bounds__(256) void reduce_att2(
    const float* __restrict__ h2p, const float* __restrict__ asrc,
    const float* __restrict__ adst, float* __restrict__ h2,
    float* __restrict__ as2, float* __restrict__ ad2, int Mpad, int n) {
  int w = threadIdx.x >> 6, lane = threadIdx.x & 63;
  int row = blockIdx.x * 4 + w;
  if (row >= n) return;
  float s = 0.f;
#pragma unroll
  for (int sk = 0; sk < 4; ++sk) s += h2p[((size_t)sk * Mpad + row) * 64 + lane];
  h2[(size_t)row * 64 + lane] = s;
  float ds = s * asrc[lane], dd = s * adst[lane];
  for (int o = 32; o; o >>= 1) { ds += __shfl_xor(ds, o); dd += __shfl_xor(dd, o); }
  if (lane == 0) { as2[row] = ds; ad2[row] = dd; }
}

// ---- layer-2 gather: one wave per node, fused e+den -----------------------

__global__ __launch_bounds__(256) void agg2_gather(
    const float* __restrict__ h2, const float* __restrict__ as2,
    const float* __restrict__ ad2, const int* __restrict__ offsets,
    const int* __restrict__ list, const float* __restrict__ b2,
    float* __restrict__ out, int n) {
  const int wid = threadIdx.x >> 6, lane = threadIdx.x & 63;
  const int node = blockIdx.x * 4 + wid;
  if (node >= n) return;
  const int beg = offsets[node], end = offsets[node + 1];
  const float ad = ad2[node];
  const int cb = (lane & 15) * 4;  // 4 channels per lane
  const int jo = lane >> 4;        // row-in-quad

  float4 acc = make_float4(0.f, 0.f, 0.f, 0.f);
  float den = 0.f;
  for (int j = beg + jo; j < end; j += 4) {
    int s = list[j];
    float e = __expf(lrelu(as2[s] + ad));
    den += e;
    float4 v = *(const float4*)&h2[(size_t)s * 64 + cb];
    acc.x += e * v.x; acc.y += e * v.y; acc.z += e * v.z; acc.w += e * v.w;
  }
  acc.x += __shfl_xor(acc.x, 16); acc.y += __shfl_xor(acc.y, 16);
  acc.z += __shfl_xor(acc.z, 16); acc.w += __shfl_xor(acc.w, 16);
  den += __shfl_xor(den, 16);
  acc.x += __shfl_xor(acc.x, 32); acc.y += __shfl_xor(acc.y, 32);
  acc.z += __shfl_xor(acc.z, 32); acc.w += __shfl_xor(acc.w, 32);
  den += __shfl_xor(den, 32);
  if (jo == 0) {
    float inv = 1.f / (den + 1e-16f);
    float4 r;
    r.x = acc.x * inv + b2[cb];
    r.y = acc.y * inv + b2[cb + 1];
    r.z = acc.z * inv + b2[cb + 2];
    r.w = acc.w * inv + b2[cb + 3];
    *(float4*)&out[(size_t)node * 64 + cb] = r;
  }
}

// ---------------------------------------------------------------------------

extern "C" void kernel_launch(void* const* d_in, const int* in_sizes, int n_in,
                              void* d_out, int out_size, void* d_ws, size_t ws_size,
                              hipStream_t stream) {
  const float* x     = (const float*)d_in[0];
  const int*   ei    = (const int*)d_in[1];
  const float* W1    = (const float*)d_in[2];
  const float* asrc1 = (const float*)d_in[3];
  const float* adst1 = (const float*)d_in[4];
  const float* b1    = (const float*)d_in[5];
  const float* W2    = (const float*)d_in[6];
  const float* asrc2 = (const float*)d_in[7];
  const float* adst2 = (const float*)d_in[8];
  const float* b2    = (const float*)d_in[9];
  float* out = (float*)d_out;

  const int N = in_sizes[0] / 256;
  const int E = in_sizes[1] / 2;
  const int T = E + N;  // edges + self loops
  const int MBB = (N + 127) / 128;  // gemm1 M-blocks
  const int Mpad = MBB * 128;
  const int MB1 = Mpad / 64;        // 64-row pack blocks
  const int NB = (N + 255) / 256;

  char* p = (char*)d_ws;
  auto bump = [&](size_t bytes) {
    char* r = p;
    p += (bytes + 255) & ~(size_t)255;
    return r;
  };
  int* counts  = (int*)bump((size_t)N * 4);
  int* offsets = (int*)bump((size_t)(N + 1) * 4);
  int* cursors = (int*)bump((size_t)N * 4);
  int* bsum    = (int*)bump((size_t)NB * 4);
  int* list    = (int*)bump((size_t)T * 4);
  unsigned short* xpk  = (unsigned short*)bump((size_t)Mpad * 256 * 2);   // hi only
  unsigned short* w1pk = (unsigned short*)bump((size_t)8 * 8 * 16 * 512 * 2);
  unsigned short* h1b  = (unsigned short*)bump((size_t)Mpad * 1024 * 2);
  float* as1           = (float*)bump((size_t)Mpad * 8 * 4);
  float* ad1           = (float*)bump((size_t)Mpad * 8 * 4);
  unsigned short* o1pk = (unsigned short*)bump((size_t)Mpad * 2048 * 2);  // hi+lo
  unsigned short* w2pk = (unsigned short*)bump((size_t)32 * 8 * 512 * 2);
  float* as2           = (float*)bump((size_t)Mpad * 4);
  float* ad2           = (float*)bump((size_t)Mpad * 4);
  // aliases (safe: single-stream ordering; last reader precedes first writer)
  float* h2p = (float*)h1b;   // 4*Mpad*64*4B = Mpad*1KB <= Mpad*2KB
  float* h2  = (float*)o1pk;  // Mpad*64*4B = Mpad*256B <= Mpad*4KB (read after gemm2)

  // CSR + packing
  hipMemsetAsync(counts, 0, (size_t)N * 4, stream);
  {
    int gridsz = (E + 255) / 256 + MB1 * 8 + 64 + 32;
    prep_fused<<<gridsz, 256, 0, stream>>>(ei, counts, E, x, xpk, N, MB1,
                                           W1, w1pk, W2, w2pk);
  }
  scan_blk<<<NB, 256, 0, stream>>>(counts, offsets, bsum, N);
  scan_apply<<<NB, 256, 0, stream>>>(offsets, cursors, bsum, NB, N);
  fill_all<<<(E + N + 255) / 256, 256, 0, stream>>>(ei, cursors, offsets, list, E, N);

  // layer 1
  gemm1_att<<<dim3(MBB, 8), 512, 49152, stream>>>(xpk, w1pk, asrc1, adst1, h1b, as1, ad1);
  agg1_gather<<<(N + 3) / 4, 256, 0, stream>>>(h1b, as1, ad1, offsets, list, b1, o1pk, N);

  // layer 2
  gemm2_splitk<<<dim3(Mpad / 64, 4), 256, 32768, stream>>>(o1pk, w2pk, h2p, Mpad);
  reduce_att2<<<(N + 3) / 4, 256, 0, stream>>>(h2p, asrc2, adst2, h2, as2, ad2, Mpad, N);
  agg2_gather<<<(N + 3) / 4, 256, 0, stream>>>(h2, as2, ad2, offsets, list, b2, out, N);
}